// Round 8
// baseline (1481.274 us; speedup 1.0000x reference)
//
#include <hip/hip_runtime.h>
#include <math.h>

#define NN   20000
#define EE   80000
#define ELP  100000   // EE + NN self loops
#define NGR  64
#define EMB  780
#define W3   2340
#define EMBP 832      // 780 padded to mult of 64
#define W3P  2368     // 2340 padded to mult of 64
#define NZ   (W3+8)   // dvec length (incl. attention-correction slots)

static inline int cdiv_i(long long a, long long b){ return (int)((a + b - 1) / b); }

typedef _Float16 f16;
typedef _Float16 f16x4 __attribute__((ext_vector_type(4)));
typedef _Float16 f16x8 __attribute__((ext_vector_type(8)));
typedef float    f32x4 __attribute__((ext_vector_type(4)));

__device__ __forceinline__ void async_ld16(const f16* g, f16* l){
    __builtin_amdgcn_global_load_lds(
        (const __attribute__((address_space(1))) unsigned int*)g,
        (__attribute__((address_space(3))) unsigned int*)l,
        16, 0, 0);
}

// ---------------- utility kernels ----------------
__global__ void k_zero_f32(float* p, int n){
    int i = blockIdx.x*256 + threadIdx.x; if (i < n) p[i] = 0.f;
}
__global__ void k_zero_i32(int* p, int n){
    int i = blockIdx.x*256 + threadIdx.x; if (i < n) p[i] = 0;
}

// W [K,N] fp32 -> Wt [N,KP] f16 (scaled by sc for BN fold); also accumulates
// dvec[n] += sum_k sh[k]*W[k,n] (RAW W) via per-tile reduction + 32 atomics.
__global__ void k_transpose(const float* __restrict__ W, f16* __restrict__ Wt,
                            const float* __restrict__ sc, const float* __restrict__ sh,
                            float* __restrict__ dvec, int K, int N, int KP){
    __shared__ float T[32][33];
    __shared__ float D[8][33];
    int n0 = blockIdx.x*32, k0 = blockIdx.y*32;
    int tx = threadIdx.x, ty = threadIdx.y;   // 32 x 8
    float raw[4];
#pragma unroll
    for (int r = 0; r < 4; r++){
        int k = k0 + ty + r*8;
        float w = 0.f;
        if (k < K && n0 + tx < N) w = W[(size_t)k*N + n0 + tx];
        raw[r] = w;
        T[ty + r*8][tx] = sc ? w * ((k < K) ? sc[k] : 0.f) : w;
    }
    if (sh){
        float p = 0.f;
#pragma unroll
        for (int r = 0; r < 4; r++){
            int k = k0 + ty + r*8;
            if (k < K) p += sh[k] * raw[r];
        }
        D[ty][tx] = p;
    }
    __syncthreads();
#pragma unroll
    for (int r = 0; r < 4; r++){
        int n = n0 + ty + r*8;
        int k = k0 + tx;
        if (n < N && k < KP) Wt[(size_t)n*KP + k] = (f16)T[tx][ty + r*8];
    }
    if (sh && ty == 0 && n0 + tx < N){
        float s = 0.f;
#pragma unroll
        for (int j = 0; j < 8; j++) s += D[j][tx];
        atomicAdd(&dvec[n0 + tx], s);
    }
}

// Attention fold: Wt[N+i][k] = sc[k] * sum_c W[k, h*EMB+c] * att[i][c]
// block 0 additionally computes dvec[N+i] (rank-1 correction), dvec core already final.
__global__ void k_wvec(const float* __restrict__ W, const float* __restrict__ asrc,
                       const float* __restrict__ adst, const float* __restrict__ sc,
                       f16* __restrict__ Wt, float* __restrict__ dvec,
                       int K, int N, int KP, int H){
    int k = blockIdx.x*4 + (threadIdx.x >> 6);
    int lane = threadIdx.x & 63;
    if (k < K){
        const float* row = W + (size_t)k*N;
        float acc[6];
#pragma unroll
        for (int i = 0; i < 6; i++) acc[i] = 0.f;
        for (int c = lane; c < EMB; c += 64){
            for (int h = 0; h < H; h++){
                float wv = row[h*EMB + c];
                acc[h]     += wv * asrc[h*EMB + c];
                acc[H + h] += wv * adst[h*EMB + c];
            }
        }
        float s = sc ? sc[k] : 1.f;
        for (int i = 0; i < 2*H; i++){
            float v = acc[i];
#pragma unroll
            for (int off = 32; off; off >>= 1) v += __shfl_xor(v, off);
            if (lane == 0) Wt[(size_t)(N + i)*KP + k] = (f16)(v * s);
        }
    }
    if (blockIdx.x == 0){
        int wv = threadIdx.x >> 6;
        for (int i = wv; i < 2*H; i += 4){
            int h = (i < H) ? i : (i - H);
            const float* att = (i < H) ? (asrc + h*EMB) : (adst + h*EMB);
            float s = 0.f;
            for (int c = lane; c < EMB; c += 64) s += dvec[h*EMB + c] * att[c];
#pragma unroll
            for (int off = 32; off; off >>= 1) s += __shfl_xor(s, off);
            if (lane == 0) dvec[N + i] = s;
        }
    }
}

// ---------------- h0 (f16x4 stores) ----------------
__global__ void k_build_h(const float* __restrict__ x, const float* __restrict__ tW,
                          const float* __restrict__ tb, f16* __restrict__ h){
    int idx = blockIdx.x*256 + threadIdx.x;
    int total = NN*(EMBP/4);
    if (idx >= total) return;
    int n = idx / (EMBP/4);
    int c0 = (idx - n*(EMBP/4))*4;
    const float* xr = x + (size_t)n*772;
    f16x4 o;
#pragma unroll
    for (int j = 0; j < 4; j++){
        int c = c0 + j; float v;
        if (c < 768) v = xr[c];
        else if (c < EMB){
            int t = c - 768;
            v = tb[t] + xr[768]*tW[t] + xr[769]*tW[12+t] + xr[770]*tW[24+t] + xr[771]*tW[36+t];
        } else v = 0.f;
        o[j] = (f16)v;
    }
    *(f16x4*)(h + (size_t)n*EMBP + c0) = o;
}

// ---------------- CSR build ----------------
__global__ void k_deg(const int* __restrict__ ei, int* __restrict__ deg){
    int k = blockIdx.x*256 + threadIdx.x; if (k >= ELP) return;
    int d = (k < EE) ? ei[EE + k] : (k - EE);
    atomicAdd(&deg[d], 1);
}

// 20 nodes/thread local sum -> single 1024-scan -> write prefixes into rp AND cursor(deg, in place)
__global__ __launch_bounds__(1024) void k_scan(int* __restrict__ deg, int* __restrict__ rp){
    __shared__ int part[1024];
    int tid = threadIdx.x;
    int i0 = tid*20;
    int n = (i0 < NN) ? min(20, NN - i0) : 0;
    int s = 0;
    for (int k = 0; k < n; k++) s += deg[i0+k];
    part[tid] = s; __syncthreads();
    for (int off = 1; off < 1024; off <<= 1){
        int t = (tid >= off) ? part[tid-off] : 0;
        __syncthreads();
        part[tid] += t;
        __syncthreads();
    }
    int run = part[tid] - s;   // exclusive prefix
    for (int k = 0; k < n; k++){
        int d = deg[i0+k];
        rp[i0+k] = run;
        deg[i0+k] = run;       // cursor init
        run += d;
    }
    if (tid == 1023) rp[NN] = part[1023];
}

__global__ void k_fill(const int* __restrict__ ei, int* __restrict__ cursor, int* __restrict__ csrc){
    int k = blockIdx.x*256 + threadIdx.x; if (k >= ELP) return;
    int s, d;
    if (k < EE){ s = ei[k]; d = ei[EE + k]; } else { s = k - EE; d = s; }
    int pos = atomicAdd(&cursor[d], 1);
    csrc[pos] = s;
}

__global__ void k_grp(const int* __restrict__ batch, int* __restrict__ grp){
    int g = blockIdx.x*256 + threadIdx.x; if (g > NGR) return;
    int lo = 0, hi = NN;
    while (lo < hi){ int mid = (lo+hi)>>1; if (batch[mid] < g) lo = mid+1; else hi = mid; }
    grp[g] = lo;
}

// ====== 128x256 MFMA GEMM, BK=32, ring-3 LDS, 2 blocks/CU (verified round 4) ======
__global__ __launch_bounds__(512, 4) void k_gemmT(const f16* __restrict__ A,
                                                  const f16* __restrict__ Bt,
                                                  const float* __restrict__ dvec,
                                                  f16* __restrict__ C,
                                                  float* __restrict__ a_sd,
                                                  int M, int N, int NB, int H,
                                                  int KP, int SN, int Mtiles, int NT){
    __shared__ f16 smem[36864];        // A ring [0,12288): 3x4096; B ring [12288,36864): 3x8192
    f16* sB = smem + 12288;

    // bijective XCD-chunked swizzle, mt-major: one XCD works a contiguous M strip (A L2 reuse)
    int nwg = Mtiles*NT;
    int bid = blockIdx.x;
    int q = nwg >> 3, r = nwg & 7, xcd = bid & 7, lin = bid >> 3;
    int wg = (xcd < r ? xcd*(q+1) : r*(q+1) + (xcd - r)*q) + lin;
    int mt = wg / NT, nt = wg - mt*NT;
    int m0 = mt*128, n0 = nt*256;

    int tid = threadIdx.x;
    int w = tid >> 6, lane = tid & 63;
    int lm = lane & 15, lq = lane >> 4;
    int wm = w >> 2, wn = w & 3;       // wave tile: rows wm*64..+64, cols wn*64..+64

    // staging (linear LDS dest, inverse-swizzled global K-chunk):
    // A: 1 call/wave, rows w*16..+15 ; B: 2 calls/wave, rows w*32..+31
    int kqs = ((lane & 3) ^ ((lane >> 3) & 3)) * 8;
    const f16* gA0 = A  + (size_t)min(m0 + w*16 + (lane >> 2), M-1)*KP + kqs;
    const f16* gB0 = Bt + (size_t)min(n0 + w*32 + (lane >> 2), NB-1)*KP + kqs;
    const f16* gB1 = Bt + (size_t)min(n0 + w*32 + 16 + (lane >> 2), NB-1)*KP + kqs;
    int sa0 = w*512;                   // A dest (f16 units) within buffer
    int sb0 = w*1024, sb1 = w*1024 + 512;

    // fragment read offsets (swizzled kq), row stride 32 f16
    int swz  = (lq ^ ((lm >> 1) & 3)) * 8;
    int aoff = (wm*64 + lm)*32 + swz;
    int boff = (wn*64 + lm)*32 + swz;

    f32x4 acc[4][4];
#pragma unroll
    for (int i = 0; i < 4; i++)
#pragma unroll
        for (int j = 0; j < 4; j++) acc[i][j] = (f32x4)0.f;

    int KT = KP >> 5;   // K-tiles of 32; >= 26 for all layers

    // prologue: stage tiles 0 and 1; drain tile0's 3 calls, keep tile1's in flight
    async_ld16(gA0,      &smem[sa0]);
    async_ld16(gB0,      &sB[sb0]);
    async_ld16(gB1,      &sB[sb1]);
    async_ld16(gA0 + 32, &smem[4096 + sa0]);
    async_ld16(gB0 + 32, &sB[8192 + sb0]);
    async_ld16(gB1 + 32, &sB[8192 + sb1]);
    asm volatile("s_waitcnt vmcnt(3)" ::: "memory");
    __builtin_amdgcn_s_barrier();

    int cur = 0, nx2 = 2;
    for (int t = 0; t < KT; t++){
        int ac = cur*4096, bc = cur*8192;
        f16x8 aF[4], bF[4];
#pragma unroll
        for (int i = 0; i < 4; i++) aF[i] = *(const f16x8*)&smem[ac + aoff + i*512];
#pragma unroll
        for (int i = 0; i < 4; i++) bF[i] = *(const f16x8*)&sB[bc + boff + i*512];
        bool s2 = (t+2 < KT);
        if (s2){
            int ko2 = (t+2)*32;
            int a2 = nx2*4096, b2 = nx2*8192;
            async_ld16(gA0 + ko2, &smem[a2 + sa0]);
            async_ld16(gB0 + ko2, &sB[b2 + sb0]);
            async_ld16(gB1 + ko2, &sB[b2 + sb1]);
        }
        __builtin_amdgcn_s_setprio(1);
#pragma unroll
        for (int i = 0; i < 4; i++)
#pragma unroll
            for (int j = 0; j < 4; j++)
                acc[i][j] = __builtin_amdgcn_mfma_f32_16x16x32_f16(aF[i], bF[j], acc[i][j], 0, 0, 0);
        __builtin_amdgcn_s_setprio(0);
        if (s2) asm volatile("s_waitcnt vmcnt(3)" ::: "memory");
        else    asm volatile("s_waitcnt vmcnt(0)" ::: "memory");
        __builtin_amdgcn_s_barrier();
        cur = (cur == 2) ? 0 : cur + 1;
        nx2 = (nx2 == 2) ? 0 : nx2 + 1;
    }

    // attention columns ([N,NB)) -> a_sd directly (registers only)
#pragma unroll
    for (int mi = 0; mi < 4; mi++){
#pragma unroll
        for (int ni = 0; ni < 4; ni++){
            int col = n0 + wn*64 + ni*16 + lm;
            if (col >= N && col < NB){
                int jc = col - N;
                int idx = (jc < H) ? jc : (3 + jc - H);
                float dv = dvec[col];
                int rbase = m0 + wm*64 + mi*16 + lq*4;
#pragma unroll
                for (int rr = 0; rr < 4; rr++){
                    int row = rbase + rr;
                    if (row < M) a_sd[(size_t)row*6 + idx] = acc[mi][ni][rr] + dv;
                }
            }
        }
    }

    // C tile (128x256) -> LDS stride 264 -> coalesced f16x8 stores
    float dv4[4];
#pragma unroll
    for (int ni = 0; ni < 4; ni++){
        int gcol = n0 + wn*64 + ni*16 + lm;
        dv4[ni] = (gcol < N) ? dvec[gcol] : 0.f;
    }
    int ncols = min(256, N - n0);
#pragma unroll
    for (int mi = 0; mi < 4; mi++){
#pragma unroll
        for (int ni = 0; ni < 4; ni++){
            int colL = wn*64 + ni*16 + lm;
#pragma unroll
            for (int rr = 0; rr < 4; rr++){
                int rowL = wm*64 + mi*16 + lq*4 + rr;
                smem[rowL*264 + colL] = (f16)(acc[mi][ni][rr] + dv4[ni]);
            }
        }
    }
    // drain LDS writes before the barrier so other waves' reads see them (race fix, round 4)
    asm volatile("s_waitcnt lgkmcnt(0)" ::: "memory");
    __builtin_amdgcn_s_barrier();
#pragma unroll
    for (int it = 0; it < 8; it++){
        int ch = tid + it*512;            // 4096 chunks: 128 rows x 32 col-chunks
        int rowL = ch >> 5, cc = (ch & 31)*8;
        int grow = m0 + rowL;
        if (grow < M && cc < ncols){
            if (cc + 8 <= ncols){
                f16x8 v = *(f16x8*)&smem[rowL*264 + cc];
                *(f16x8*)(C + (size_t)grow*SN + n0 + cc) = v;
            } else {
                for (int jj = cc; jj < ncols; jj++)
                    C[(size_t)grow*SN + n0 + jj] = smem[rowL*264 + jj];
            }
        }
    }
}

// ====== 128x128 MFMA GEMM (L2 layer): 4 waves, ring-3, 3 blocks/CU ======
// Same hazard structure as k_gemmT (4 staging calls/tile -> vmcnt(4)); fixes the
// 628-block / 512-slot tail (1099 smaller blocks -> 1.43 generations).
__global__ __launch_bounds__(256, 3) void k_gemmS(const f16* __restrict__ A,
                                                  const f16* __restrict__ Bt,
                                                  const float* __restrict__ dvec,
                                                  f16* __restrict__ C,
                                                  float* __restrict__ a_sd,
                                                  int M, int N, int NB, int H,
                                                  int KP, int SN, int Mtiles, int NT){
    __shared__ f16 smem[24576];        // A ring [0,12288): 3x4096; B ring [12288,24576): 3x4096
    f16* sB = smem + 12288;

    int nwg = Mtiles*NT;
    int bid = blockIdx.x;
    int q = nwg >> 3, r = nwg & 7, xcd = bid & 7, lin = bid >> 3;
    int wg = (xcd < r ? xcd*(q+1) : r*(q+1) + (xcd - r)*q) + lin;
    int mt = wg / NT, nt = wg - mt*NT;
    int m0 = mt*128, n0 = nt*128;

    int tid = threadIdx.x;
    int w = tid >> 6, lane = tid & 63;      // 4 waves
    int lm = lane & 15, lq = lane >> 4;
    int wm = w >> 1, wn = w & 1;            // wave tile 64x64: rows wm*64.., cols wn*64..

    // staging: A rows 128: wave w rows w*32..+31 (2 calls); B same.
    int kqs = ((lane & 3) ^ ((lane >> 3) & 3)) * 8;
    const f16* gA0 = A  + (size_t)min(m0 + w*32 + (lane >> 2), M-1)*KP + kqs;
    const f16* gA1 = A  + (size_t)min(m0 + w*32 + 16 + (lane >> 2), M-1)*KP + kqs;
    const f16* gB0 = Bt + (size_t)min(n0 + w*32 + (lane >> 2), NB-1)*KP + kqs;
    const f16* gB1 = Bt + (size_t)min(n0 + w*32 + 16 + (lane >> 2), NB-1)*KP + kqs;
    int sa0 = w*1024, sa1 = w*1024 + 512;
    int sb0 = w*1024, sb1 = w*1024 + 512;

    int swz  = (lq ^ ((lm >> 1) & 3)) * 8;
    int aoff = (wm*64 + lm)*32 + swz;
    int boff = (wn*64 + lm)*32 + swz;

    f32x4 acc[4][4];
#pragma unroll
    for (int i = 0; i < 4; i++)
#pragma unroll
        for (int j = 0; j < 4; j++) acc[i][j] = (f32x4)0.f;

    int KT = KP >> 5;

    // prologue: tiles 0 and 1 (4 calls each); drain tile0, keep tile1 in flight
    async_ld16(gA0,      &smem[sa0]);        async_ld16(gA1,      &smem[sa1]);
    async_ld16(gB0,      &sB[sb0]);          async_ld16(gB1,      &sB[sb1]);
    async_ld16(gA0 + 32, &smem[4096 + sa0]); async_ld16(gA1 + 32, &smem[4096 + sa1]);
    async_ld16(gB0 + 32, &sB[4096 + sb0]);   async_ld16(gB1 + 32, &sB[4096 + sb1]);
    asm volatile("s_waitcnt vmcnt(4)" ::: "memory");
    __builtin_amdgcn_s_barrier();

    int cur = 0, nx2 = 2;
    for (int t = 0; t < KT; t++){
        int ac = cur*4096, bc = cur*4096;
        f16x8 aF[4], bF[4];
#pragma unroll
        for (int i = 0; i < 4; i++) aF[i] = *(const f16x8*)&smem[ac + aoff + i*512];
#pragma unroll
        for (int i = 0; i < 4; i++) bF[i] = *(const f16x8*)&sB[bc + boff + i*512];
        bool s2 = (t+2 < KT);
        if (s2){
            int ko2 = (t+2)*32;
            int a2 = nx2*4096, b2 = nx2*4096;
            async_ld16(gA0 + ko2, &smem[a2 + sa0]); async_ld16(gA1 + ko2, &smem[a2 + sa1]);
            async_ld16(gB0 + ko2, &sB[b2 + sb0]);   async_ld16(gB1 + ko2, &sB[b2 + sb1]);
        }
        __builtin_amdgcn_s_setprio(1);
#pragma unroll
        for (int i = 0; i < 4; i++)
#pragma unroll
            for (int j = 0; j < 4; j++)
                acc[i][j] = __builtin_amdgcn_mfma_f32_16x16x32_f16(aF[i], bF[j], acc[i][j], 0, 0, 0);
        __builtin_amdgcn_s_setprio(0);
        if (s2) asm volatile("s_waitcnt vmcnt(4)" ::: "memory");
        else    asm volatile("s_waitcnt vmcnt(0)" ::: "memory");
        __builtin_amdgcn_s_barrier();
        cur = (cur == 2) ? 0 : cur + 1;
        nx2 = (nx2 == 2) ? 0 : nx2 + 1;
    }

    // attention columns
#pragma unroll
    for (int mi = 0; mi < 4; mi++){
#pragma unroll
        for (int ni = 0; ni < 4; ni++){
            int col = n0 + wn*64 + ni*16 + lm;
            if (col >= N && col < NB){
                int jc = col - N;
                int idx = (jc < H) ? jc : (3 + jc - H);
                float dv = dvec[col];
                int rbase = m0 + wm*64 + mi*16 + lq*4;
#pragma unroll
                for (int rr = 0; rr < 4; rr++){
                    int row = rbase + rr;
                    if (row < M) a_sd[(size_t)row*6 + idx] = acc[mi][ni][rr] + dv;
                }
            }
        }
    }

    // C tile (128x128) -> LDS stride 136 -> coalesced stores
    float dv4[4];
#pragma unroll
    for (int ni = 0; ni < 4; ni++){
        int gcol = n0 + wn*64 + ni*16 + lm;
        dv4[ni] = (gcol < N) ? dvec[gcol] : 0.f;
    }
    int ncols = min(128, N - n0);
#pragma unroll
    for (int mi = 0; mi < 4; mi++){
#pragma unroll
        for (int ni = 0; ni < 4; ni++){
            int colL = wn*64 + ni*16 + lm;
#pragma unroll
            for (int rr = 0; rr < 4; rr++){
                int rowL = wm*64 + mi*16 + lq*4 + rr;
                smem[rowL*136 + colL] = (f16)(acc[mi][ni][rr] + dv4[ni]);
            }
        }
    }
    asm volatile("s_waitcnt lgkmcnt(0)" ::: "memory");
    __builtin_amdgcn_s_barrier();
#pragma unroll
    for (int it = 0; it < 8; it++){
        int ch = tid + it*256;            // 2048 chunks: 128 rows x 16 col-chunks
        int rowL = ch >> 4, cc = (ch & 15)*8;
        int grow = m0 + rowL;
        if (grow < M && cc < ncols){
            if (cc + 8 <= ncols){
                f16x8 v = *(f16x8*)&smem[rowL*136 + cc];
                *(f16x8*)(C + (size_t)grow*SN + n0 + cc) = v;
            } else {
                for (int jj = cc; jj < ncols; jj++)
                    C[(size_t)grow*SN + n0 + jj] = smem[rowL*136 + jj];
            }
        }
    }
}

// ---- phase 1: per-node softmax -> per-edge alpha (f32) ----
template<int H>
__global__ __launch_bounds__(256) void k_alpha(const int* __restrict__ rp, const int* __restrict__ csrc,
                                               const float* __restrict__ a_sd, float* __restrict__ alpha){
    int n = blockIdx.x*4 + (threadIdx.x >> 6);
    if (n >= NN) return;
    int lane = threadIdx.x & 63;
    int beg = rp[n], deg = rp[n+1] - beg;

    float adv[H];
#pragma unroll
    for (int h = 0; h < H; h++) adv[h] = a_sd[(size_t)n*6 + 3 + h];

    bool act0 = lane < deg;
    int sl0 = 0; float t0[H];
    if (act0){
        sl0 = csrc[beg + lane];
#pragma unroll
        for (int h = 0; h < H; h++){
            float t = a_sd[(size_t)sl0*6 + h] + adv[h];
            t0[h] = t > 0.f ? t : 0.2f*t;
        }
    } else {
#pragma unroll
        for (int h = 0; h < H; h++) t0[h] = -1e30f;
    }

    float mx[H];
#pragma unroll
    for (int h = 0; h < H; h++) mx[h] = t0[h];
    for (int base = 64; base < deg; base += 64){
        int e = base + lane;
        if (e < deg){
            int s = csrc[beg + e];
#pragma unroll
            for (int h = 0; h < H; h++){
                float t = a_sd[(size_t)s*6 + h] + adv[h];
                t = t > 0.f ? t : 0.2f*t;
                mx[h] = fmaxf(mx[h], t);
            }
        }
    }
#pragma unroll
    for (int off = 32; off; off >>= 1)
#pragma unroll
        for (int h = 0; h < H; h++) mx[h] = fmaxf(mx[h], __shfl_xor(mx[h], off));

    float dn[H];
#pragma unroll
    for (int h = 0; h < H; h++) dn[h] = act0 ? expf(t0[h] - mx[h]) : 0.f;
    for (int base = 64; base < deg; base += 64){
        int e = base + lane;
        if (e < deg){
            int s = csrc[beg + e];
#pragma unroll
            for (int h = 0; h < H; h++){
                float t = a_sd[(size_t)s*6 + h] + adv[h];
                t = t > 0.f ? t : 0.2f*t;
                dn[h] += expf(t - mx[h]);
            }
        }
    }
#pragma unroll
    for (int off = 32; off; off >>= 1)
#pragma unroll
        for (int h = 0; h < H; h++) dn[h] += __shfl_xor(dn[h], off);
    float inv[H];
#pragma unroll
    for (int h = 0; h < H; h++) inv[h] = 1.f / (dn[h] + 1e-16f);

    if (act0){
        if (H == 3){
            float4 o;
            o.x = expf(t0[0]-mx[0])*inv[0];
            o.y = expf(t0[1]-mx[1])*inv[1];
            o.z = expf(t0[2]-mx[2])*inv[2];
            o.w = 0.f;
            *(float4*)(alpha + (size_t)(beg+lane)*4) = o;
        } else {
            alpha[beg+lane] = expf(t0[0]-mx[0])*inv[0];
        }
    }
    for (int base = 64; base < deg; base += 64){
        int e = base + lane;
        if (e < deg){
            int s = csrc[beg + e];
            float av[H];
#pragma unroll
            for (int h = 0; h < H; h++){
                float t = a_sd[(size_t)s*6 + h] + adv[h];
                t = t > 0.f ? t : 0.2f*t;
                av[h] = expf(t - mx[h]) * inv[h];
            }
            if (H == 3){
                float4 o; o.x = av[0]; o.y = av[1]; o.z = av[2]; o.w = 0.f;
                *(float4*)(alpha + (size_t)(beg+e)*4) = o;
            } else {
                alpha[beg+e] = av[0];
            }
        }
    }
}

// ---- phase 2: gather via DMA ring: 4 gathered rows ALWAYS in flight per wave ----
// Wave-per-(node, 512-col group). Per 64-edge chunk: one per-lane preload of
// (src, alpha) into regs (its vmcnt slots drain first - FIFO), then a 6-slot x 1KB
// per-wave LDS ring: issue 4 row-DMAs ahead; steady loop = vmcnt(3) -> ds_read
// slot -> 16 FMA -> shfl next src -> issue into slot (j+4)%6 (reuse distance 2
// iters, ds_read long retired). Chunk boundary drains vmcnt(0). Edge order per
// column identical to all prior rounds -> same FP accumulation order.
template<int H>
__global__ __launch_bounds__(256) void k_gather2(const f16* __restrict__ hp, const int* __restrict__ rp,
                                                 const int* __restrict__ csrc, const float* __restrict__ alpha,
                                                 const float* __restrict__ bias, f16* __restrict__ y,
                                                 int SP, int W){
    __shared__ f16 ring[12288];          // 4 waves x 6 slots x 512 f16 (1KB)
    int w = threadIdx.x >> 6, lane = threadIdx.x & 63;
    int n = blockIdx.x*4 + w;
    if (n >= NN) return;
    int cb = blockIdx.y*512;
    int c = cb + lane*8;
    bool cok = c < SP;
    int beg = rp[n], deg = rp[n+1] - beg;
    f16* slot = ring + w*3072;

    int hl = 0, hh = 0, nsp = 8;
    if (H == 3){
        hl = min(c/EMB, 2); hh = min((c+7)/EMB, 2);
        nsp = (hh > hl) ? (EMB*(hl+1) - c) : 8;
    }
    float acc[8];
#pragma unroll
    for (int j = 0; j < 8; j++) acc[j] = 0.f;

    const f16* hpc = hp + cb + lane*8;   // per-lane column pointer within window

    for (int base = 0; base < deg; base += 64){
        int cnt = min(64, deg - base);
        int e = base + lane;
        int sl = 0; float a0 = 0.f, a1 = 0.f, a2 = 0.f;
        if (e < deg){
            sl = csrc[beg + e];
            if (H == 3){
                float4 q = *(const float4*)(alpha + (size_t)(beg+e)*4);
                a0 = q.x; a1 = q.y; a2 = q.z;
            } else {
                a0 = alpha[beg + e];
            }
        }
        // prologue: issue up to 4 DMAs (slots 0..P-1)
        int P = min(4, cnt);
        for (int j = 0; j < P; j++){
            int s = __shfl(sl, j);
            async_ld16(hpc + (size_t)s*SP, slot + j*512);
        }
        int M = cnt - 4; if (M < 0) M = 0;
        int rc = 0, ri = 4;              // consume slot / issue slot counters (mod 6)
        for (int j = 0; j < M; j++){
            asm volatile("s_waitcnt vmcnt(3)" ::: "memory");   // DMA j complete (FIFO; preloads drain first)
            f16x8 v = *(const f16x8*)(slot + rc*512 + lane*8);
            float b0 = __shfl(a0, j);
            float lo, hi;
            if (H == 3){
                float b1 = __shfl(a1, j), b2 = __shfl(a2, j);
                lo = (hl==0)?b0:((hl==1)?b1:b2);
                hi = (hh==0)?b0:((hh==1)?b1:b2);
            } else { lo = b0; hi = b0; }
            if (cok){
#pragma unroll
                for (int jj = 0; jj < 8; jj++)
                    acc[jj] += ((jj < nsp) ? lo : hi) * (float)v[jj];
            }
            int s2 = __shfl(sl, j+4);
            async_ld16(hpc + (size_t)s2*SP, slot + ri*512);
            rc = (rc == 5) ? 0 : rc + 1;
            ri = (ri == 5) ? 0 : ri + 1;
        }
        asm volatile("s_waitcnt vmcnt(0)" ::: "memory");       // drain tail (and chunk boundary)
        for (int j = M; j < cnt; j++){
            f16x8 v = *(const f16x8*)(slot + rc*512 + lane*8);
            float b0 = __shfl(a0, j);
            float lo, hi;
            if (H == 3){
                float b1 = __shfl(a1, j), b2 = __shfl(a2, j);
                lo = (hl==0)?b0:((hl==1)?b1:b2);
                hi = (hh==0)?b0:((hh==1)?b1:b2);
            } else { lo = b0; hi = b0; }
            if (cok){
#pragma unroll
                for (int jj = 0; jj < 8; jj++)
                    acc[jj] += ((jj < nsp) ? lo : hi) * (float)v[jj];
            }
            rc = (rc == 5) ? 0 : rc + 1;
        }
    }

    if (cok){
        f16x8 o;
#pragma unroll
        for (int j = 0; j < 8; j++){
            float vv = (c + j < W) ? tanhf(acc[j] + bias[c+j]) : 0.f;
            o[j] = (f16)vv;
        }
        *(f16x8*)(y + (size_t)n*SP + c) = o;
    }
}

// ---------------- BatchNorm stats: contiguous-row-range partials (no atomics) ----------------
__global__ void k_bnstat(const f16* __restrict__ y, float* __restrict__ ps,
                         float* __restrict__ pq, int W, int SP){
    int c0 = (blockIdx.x*256 + threadIdx.x)*4;
    if (c0 >= W) return;
    int slice = blockIdx.y;   // 0..127
    int r0 = (int)(((long long)NN*slice)/128);
    int r1 = (int)(((long long)NN*(slice+1))/128);
    float s[4] = {0,0,0,0}, q[4] = {0,0,0,0};
    for (int r = r0; r < r1; r++){
        f16x4 u = *(const f16x4*)(y + (size_t)r*SP + c0);
#pragma unroll
        for (int j = 0; j < 4; j++){ float v = (float)u[j]; s[j] += v; q[j] += v*v; }
    }
#pragma unroll
    for (int j = 0; j < 4; j++){
        ps[(size_t)slice*W3 + c0+j] = s[j];
        pq[(size_t)slice*W3 + c0+j] = q[j];
    }
}

// reduce partials; sc = istd*gamma, sh = beta - mu*istd*gamma; zero dvec for next layer
__global__ void k_bnfin(const float* __restrict__ ps, const float* __restrict__ pq,
                        const float* __restrict__ gamma, const float* __restrict__ beta,
                        float* __restrict__ sc, float* __restrict__ sh,
                        float* __restrict__ dvec, int W, int zn){
    int c = blockIdx.x*256 + threadIdx.x;
    if (c < W){
        float m = 0.f, q = 0.f;
        for (int s = 0; s < 128; s++){ m += ps[(size_t)s*W3 + c]; q += pq[(size_t)s*W3 + c]; }
        m *= (1.f/NN);
        float v = q * (1.f/NN) - m*m;
        float is = 1.f / sqrtf(v + 1e-5f);
        float g = gamma[c];
        sc[c] = is * g;
        sh[c] = beta[c] - m * is * g;
    }
    if (c < zn) dvec[c] = 0.f;
}

// ---------------- segmented pooling (raw y; BN folded into MLP) ----------------
__global__ void k_pool(const f16* __restrict__ h, const int* __restrict__ grp,
                       float* __restrict__ pooled){
    int g = blockIdx.x;
    int c = threadIdx.x*4;
    if (c >= EMB) return;
    int r0 = grp[g], r1 = grp[g+1];
    float s0=0.f, s1=0.f, s2=0.f, s3=0.f;
    for (int r = r0; r < r1; r++){
        f16x4 u = *(const f16x4*)(h + (size_t)r*EMBP + c);
        s0 += (float)u[0]; s1 += (float)u[1]; s2 += (float)u[2]; s3 += (float)u[3];
    }
    pooled[g*EMB + c] = s0; pooled[g*EMB + c+1] = s1;
    pooled[g*EMB + c+2] = s2; pooled[g*EMB + c+3] = s3;
}

__global__ __launch_bounds__(256) void k_mlp(const float* __restrict__ pooled, const int* __restrict__ grp,
                                             const float* __restrict__ sc, const float* __restrict__ sh,
                                             const float* __restrict__ W1, const float* __restrict__ b1,
                                             const float* __restrict__ W2, const float* __restrict__ b2,
                                             float* __restrict__ out){
    __shared__ float p[EMB];
    __shared__ float hid[128];
    int g = blockIdx.x, tid = threadIdx.x;
    int cnt = grp[g+1] - grp[g];
    float ic = 1.f / fmaxf((float)cnt, 1.f);
    for (int c = tid; c < EMB; c += 256){
        float v = pooled[g*EMB + c] * ic * sc[c] + sh[c];   // BN(mean) — affine commutes with mean
        p[c] = v > 0.f ? v : 0.f;
    }
    __syncthreads();
    if (tid < 128){
        float s = b1[tid];
        for (int k = 0; k < EMB; k++) s += p[k] * W1[k*128 + tid];
        hid[tid] = tanhf(s);
    }
    __syncthreads();
    if (tid < 64){
        float s = b2[tid];
        for (int k = 0; k < 128; k++) s += hid[k] * W2[k*64 + tid];
        out[g*64 + tid] = s;
    }
}

// ---------------- launch ----------------
extern "C" void kernel_launch(void* const* d_in, const int* in_sizes, int n_in,
                              void* d_out, int out_size, void* d_ws, size_t ws_size,
                              hipStream_t stream) {
    (void)in_sizes; (void)n_in; (void)out_size;
    const float* x    = (const float*)d_in[0];
    const int*   ei   = (const int*)  d_in[1];
    const int*   batch= (const int*)  d_in[2];
    const float* tW   = (const float*)d_in[3];
    const float* tb   = (const float*)d_in[4];
    const float* W0   = (const float*)d_in[5];
    const float* as0  = (const float*)d_in[6];
    const float* ad0  = (const float*)d_in[7];
    const float* b0   = (const float*)d_in[8];
    const float* g0   = (const float*)d_in[9];
    const float* be0  = (const float*)d_in[10];
    const float* W1   = (const float*)d_in[11];
    const float* as1  = (const float*)d_in[12];
    const float* ad1  = (const float*)d_in[13];
    const float* b1   = (const float*)d_in[14];
    const float* g1   = (const float*)d_in[15];
    const float* be1  = (const float*)d_in[16];
    const float* W2   = (const float*)d_in[17];
    const float* as2  = (const float*)d_in[18];
    const float* ad2  = (const float*)d_in[19];
    const float* b2   = (const float*)d_in[20];
    const float* g2   = (const float*)d_in[21];
    const float* be2  = (const float*)d_in[22];
    const float* mW1  = (const float*)d_in[23];
    const float* mb1  = (const float*)d_in[24];
    const float* mW2  = (const float*)d_in[25];
    const float* mb2  = (const float*)d_in[26];
    float* outp = (float*)d_out;

    size_t off = 0;
    auto carve = [&](size_t bytes) -> void* {
        void* p = (char*)d_ws + off;
        off = (off + bytes + 255) & ~(size_t)255;
        return p;
    };
    f16* big1 = (f16*)carve((size_t)NN*W3P*2);          // h / y buffers
    f16* big2 = (f16*)carve((size_t)NN*W3P*2);          // hp buffer
    f16* Wt   = (f16*)carve((size_t)NZ*W3P*2);          // transposed weights + attention rows
    float* a_sd  = (float*)carve((size_t)NN*6*4);       // [n][a_s(3), a_d(3)]
    float* psum  = (float*)carve((size_t)128*W3*4);     // bnstat partials
    float* psq   = (float*)carve((size_t)128*W3*4);
    float* sc    = (float*)carve((size_t)W3*4);
    float* sh    = (float*)carve((size_t)W3*4);
    float* dvec  = (float*)carve((size_t)NZ*4);
    float* alphab= (float*)carve((size_t)ELP*4*4);      // per-edge softmax weights (float4/H=3)
    float* pooled= (float*)carve((size_t)NGR*EMB*4);
    int*   grp   = (int*)carve((size_t)(NGR+1)*4);
    int*   deg   = (int*)carve((size_t)NN*4);           // reused as cursor
    int*   rp    = (int*)carve((size_t)(NN+1)*4);
    int*   csrc  = (int*)carve((size_t)ELP*4);

    if (ws_size < off) return;

    // CSR build
    k_zero_i32<<<cdiv_i(NN,256),256,0,stream>>>(deg, NN);
    k_deg<<<cdiv_i(ELP,256),256,0,stream>>>(ei, deg);
    k_scan<<<1,1024,0,stream>>>(deg, rp);
    k_fill<<<cdiv_i(ELP,256),256,0,stream>>>(ei, deg, csrc);
    k_grp<<<1,256,0,stream>>>(batch, grp);

    // h0 + initial dvec zero (layer 0 has no BN fold)
    k_build_h<<<cdiv_i((long long)NN*(EMBP/4),256),256,0,stream>>>(x, tW, tb, big1);
    k_zero_f32<<<cdiv_i(NZ,256),256,0,stream>>>(dvec, NZ);

    struct Layer { const float* W; const float* as; const float* ad; const float* b;
                   const float* g; const float* be; int H; int K; int KP; };
    Layer layers[3] = {
        {W0, as0, ad0, b0, g0, be0, 3, EMB, EMBP},
        {W1, as1, ad1, b1, g1, be1, 3, W3,  W3P },
        {W2, as2, ad2, b2, g2, be2, 1, W3,  W3P },
    };

    for (int L = 0; L < 3; L++){
        Layer& ly = layers[L];
        int Wout  = ly.H * EMB;                 // 2340 / 2340 / 780
        int NB    = Wout + 2*ly.H;              // + attention columns
        int SPout = (Wout == W3) ? W3P : EMBP;  // 2368 / 2368 / 832
        const float* scale = (L == 0) ? nullptr : sc;
        const float* shift = (L == 0) ? nullptr : sh;

        // Wt rows [0,Wout): scaled W^T (+ fused dvec accumulation); rows [Wout,NB): att fold
        dim3 tg(cdiv_i(Wout,32), cdiv_i(ly.KP,32));
        k_transpose<<<tg, dim3(32,8), 0, stream>>>(ly.W, Wt, scale, shift, dvec, ly.K, Wout, ly.KP);
        k_wvec<<<cdiv_i(ly.K,4),256,0,stream>>>(ly.W, ly.as, ly.ad, scale, Wt, dvec, ly.K, Wout, ly.KP, ly.H);

        // hp (+ a_s/a_d) = BN(h) @ [W | w_att]
        if (L < 2){
            int Mtiles = cdiv_i(NN,128), NT = cdiv_i(NB,256);
            k_gemmT<<<Mtiles*NT, 512, 0, stream>>>(big1, Wt, dvec, big2, a_sd,
                                                   NN, Wout, NB, ly.H, ly.KP, SPout, Mtiles, NT);
        } else {
            int Mtiles = cdiv_i(NN,128), NT = cdiv_i(NB,128);
            k_gemmS<<<Mtiles*NT, 256, 0, stream>>>(big1, Wt, dvec, big2, a_sd,
                                                   NN, Wout, NB, ly.H, ly.KP, SPout, Mtiles, NT);
        }

        // softmax -> per-edge alpha, then DMA-ring gather + bias + tanh
        dim3 gg(cdiv_i(NN,4), cdiv_i(SPout,512));
        if (ly.H == 3){
            k_alpha<3><<<cdiv_i(NN,4),256,0,stream>>>(rp, csrc, a_sd, alphab);
            k_gather2<3><<<gg,256,0,stream>>>(big2, rp, csrc, alphab, ly.b, big1, SPout, Wout);
        } else {
            k_alpha<1><<<cdiv_i(NN,4),256,0,stream>>>(rp, csrc, a_sd, alphab);
            k_gather2<1><<<gg,256,0,stream>>>(big2, rp, csrc, alphab, ly.b, big1, SPout, Wout);
        }

        // BN stats + fold coefficients (+ zero dvec for next layer)
        dim3 gs(cdiv_i(Wout/4,256), 128);
        k_bnstat<<<gs,256,0,stream>>>(big1, psum, psq, Wout, SPout);
        int zn = (L < 2) ? NZ : 0;
        k_bnfin<<<cdiv_i(Wout,256),256,0,stream>>>(psum, psq, ly.g, ly.be, sc, sh, dvec, Wout, zn);
    }

    // segmented pooling (raw y) + MLP (applies final BN affine on pooled means)
    k_pool<<<NGR,256,0,stream>>>(big1, grp, pooled);
    k_mlp<<<NGR,256,0,stream>>>(pooled, grp, sc, sh, mW1, mb1, mW2, mb2, outp);
}

// Round 9
// 1398.404 us; speedup vs baseline: 1.0593x; 1.0593x over previous
//
#include <hip/hip_runtime.h>
#include <math.h>

#define NN   20000
#define EE   80000
#define ELP  100000   // EE + NN self loops
#define NGR  64
#define EMB  780
#define W3   2340
#define EMBP 832      // 780 padded to mult of 64
#define W3P  2368     // 2340 padded to mult of 64
#define NZ   (W3+8)   // dvec length (incl. attention-correction slots)

static inline int cdiv_i(long long a, long long b){ return (int)((a + b - 1) / b); }

typedef _Float16 f16;
typedef _Float16 f16x4 __attribute__((ext_vector_type(4)));
typedef _Float16 f16x8 __attribute__((ext_vector_type(8)));
typedef float    f32x4 __attribute__((ext_vector_type(4)));

__device__ __forceinline__ void async_ld16(const f16* g, f16* l){
    __builtin_amdgcn_global_load_lds(
        (const __attribute__((address_space(1))) unsigned int*)g,
        (__attribute__((address_space(3))) unsigned int*)l,
        16, 0, 0);
}

// ---------------- utility kernels ----------------
__global__ void k_zero_f32(float* p, int n){
    int i = blockIdx.x*256 + threadIdx.x; if (i < n) p[i] = 0.f;
}
__global__ void k_zero_i32(int* p, int n){
    int i = blockIdx.x*256 + threadIdx.x; if (i < n) p[i] = 0;
}

// W [K,N] fp32 -> Wt [N,KP] f16 (scaled by sc for BN fold); also accumulates
// dvec[n] += sum_k sh[k]*W[k,n] (RAW W) via per-tile reduction + 32 atomics.
__global__ void k_transpose(const float* __restrict__ W, f16* __restrict__ Wt,
                            const float* __restrict__ sc, const float* __restrict__ sh,
                            float* __restrict__ dvec, int K, int N, int KP){
    __shared__ float T[32][33];
    __shared__ float D[8][33];
    int n0 = blockIdx.x*32, k0 = blockIdx.y*32;
    int tx = threadIdx.x, ty = threadIdx.y;   // 32 x 8
    float raw[4];
#pragma unroll
    for (int r = 0; r < 4; r++){
        int k = k0 + ty + r*8;
        float w = 0.f;
        if (k < K && n0 + tx < N) w = W[(size_t)k*N + n0 + tx];
        raw[r] = w;
        T[ty + r*8][tx] = sc ? w * ((k < K) ? sc[k] : 0.f) : w;
    }
    if (sh){
        float p = 0.f;
#pragma unroll
        for (int r = 0; r < 4; r++){
            int k = k0 + ty + r*8;
            if (k < K) p += sh[k] * raw[r];
        }
        D[ty][tx] = p;
    }
    __syncthreads();
#pragma unroll
    for (int r = 0; r < 4; r++){
        int n = n0 + ty + r*8;
        int k = k0 + tx;
        if (n < N && k < KP) Wt[(size_t)n*KP + k] = (f16)T[tx][ty + r*8];
    }
    if (sh && ty == 0 && n0 + tx < N){
        float s = 0.f;
#pragma unroll
        for (int j = 0; j < 8; j++) s += D[j][tx];
        atomicAdd(&dvec[n0 + tx], s);
    }
}

// Attention fold: Wt[N+i][k] = sc[k] * sum_c W[k, h*EMB+c] * att[i][c]
// block 0 additionally computes dvec[N+i] (rank-1 correction), dvec core already final.
__global__ void k_wvec(const float* __restrict__ W, const float* __restrict__ asrc,
                       const float* __restrict__ adst, const float* __restrict__ sc,
                       f16* __restrict__ Wt, float* __restrict__ dvec,
                       int K, int N, int KP, int H){
    int k = blockIdx.x*4 + (threadIdx.x >> 6);
    int lane = threadIdx.x & 63;
    if (k < K){
        const float* row = W + (size_t)k*N;
        float acc[6];
#pragma unroll
        for (int i = 0; i < 6; i++) acc[i] = 0.f;
        for (int c = lane; c < EMB; c += 64){
            for (int h = 0; h < H; h++){
                float wv = row[h*EMB + c];
                acc[h]     += wv * asrc[h*EMB + c];
                acc[H + h] += wv * adst[h*EMB + c];
            }
        }
        float s = sc ? sc[k] : 1.f;
        for (int i = 0; i < 2*H; i++){
            float v = acc[i];
#pragma unroll
            for (int off = 32; off; off >>= 1) v += __shfl_xor(v, off);
            if (lane == 0) Wt[(size_t)(N + i)*KP + k] = (f16)(v * s);
        }
    }
    if (blockIdx.x == 0){
        int wv = threadIdx.x >> 6;
        for (int i = wv; i < 2*H; i += 4){
            int h = (i < H) ? i : (i - H);
            const float* att = (i < H) ? (asrc + h*EMB) : (adst + h*EMB);
            float s = 0.f;
            for (int c = lane; c < EMB; c += 64) s += dvec[h*EMB + c] * att[c];
#pragma unroll
            for (int off = 32; off; off >>= 1) s += __shfl_xor(s, off);
            if (lane == 0) dvec[N + i] = s;
        }
    }
}

// ---------------- h0 (f16x4 stores) ----------------
__global__ void k_build_h(const float* __restrict__ x, const float* __restrict__ tW,
                          const float* __restrict__ tb, f16* __restrict__ h){
    int idx = blockIdx.x*256 + threadIdx.x;
    int total = NN*(EMBP/4);
    if (idx >= total) return;
    int n = idx / (EMBP/4);
    int c0 = (idx - n*(EMBP/4))*4;
    const float* xr = x + (size_t)n*772;
    f16x4 o;
#pragma unroll
    for (int j = 0; j < 4; j++){
        int c = c0 + j; float v;
        if (c < 768) v = xr[c];
        else if (c < EMB){
            int t = c - 768;
            v = tb[t] + xr[768]*tW[t] + xr[769]*tW[12+t] + xr[770]*tW[24+t] + xr[771]*tW[36+t];
        } else v = 0.f;
        o[j] = (f16)v;
    }
    *(f16x4*)(h + (size_t)n*EMBP + c0) = o;
}

// ---------------- CSR build ----------------
__global__ void k_deg(const int* __restrict__ ei, int* __restrict__ deg){
    int k = blockIdx.x*256 + threadIdx.x; if (k >= ELP) return;
    int d = (k < EE) ? ei[EE + k] : (k - EE);
    atomicAdd(&deg[d], 1);
}

// 20 nodes/thread local sum -> single 1024-scan -> write prefixes into rp AND cursor(deg, in place)
__global__ __launch_bounds__(1024) void k_scan(int* __restrict__ deg, int* __restrict__ rp){
    __shared__ int part[1024];
    int tid = threadIdx.x;
    int i0 = tid*20;
    int n = (i0 < NN) ? min(20, NN - i0) : 0;
    int s = 0;
    for (int k = 0; k < n; k++) s += deg[i0+k];
    part[tid] = s; __syncthreads();
    for (int off = 1; off < 1024; off <<= 1){
        int t = (tid >= off) ? part[tid-off] : 0;
        __syncthreads();
        part[tid] += t;
        __syncthreads();
    }
    int run = part[tid] - s;   // exclusive prefix
    for (int k = 0; k < n; k++){
        int d = deg[i0+k];
        rp[i0+k] = run;
        deg[i0+k] = run;       // cursor init
        run += d;
    }
    if (tid == 1023) rp[NN] = part[1023];
}

__global__ void k_fill(const int* __restrict__ ei, int* __restrict__ cursor, int* __restrict__ csrc){
    int k = blockIdx.x*256 + threadIdx.x; if (k >= ELP) return;
    int s, d;
    if (k < EE){ s = ei[k]; d = ei[EE + k]; } else { s = k - EE; d = s; }
    int pos = atomicAdd(&cursor[d], 1);
    csrc[pos] = s;
}

__global__ void k_grp(const int* __restrict__ batch, int* __restrict__ grp){
    int g = blockIdx.x*256 + threadIdx.x; if (g > NGR) return;
    int lo = 0, hi = NN;
    while (lo < hi){ int mid = (lo+hi)>>1; if (batch[mid] < g) lo = mid+1; else hi = mid; }
    grp[g] = lo;
}

// ====== 128x256 MFMA GEMM, BK=32, ring-3 LDS, 2 blocks/CU (verified round 4) ======
__global__ __launch_bounds__(512, 4) void k_gemmT(const f16* __restrict__ A,
                                                  const f16* __restrict__ Bt,
                                                  const float* __restrict__ dvec,
                                                  f16* __restrict__ C,
                                                  float* __restrict__ a_sd,
                                                  int M, int N, int NB, int H,
                                                  int KP, int SN, int Mtiles, int NT){
    __shared__ f16 smem[36864];        // A ring [0,12288): 3x4096; B ring [12288,36864): 3x8192
    f16* sB = smem + 12288;

    // bijective XCD-chunked swizzle, mt-major: one XCD works a contiguous M strip (A L2 reuse)
    int nwg = Mtiles*NT;
    int bid = blockIdx.x;
    int q = nwg >> 3, r = nwg & 7, xcd = bid & 7, lin = bid >> 3;
    int wg = (xcd < r ? xcd*(q+1) : r*(q+1) + (xcd - r)*q) + lin;
    int mt = wg / NT, nt = wg - mt*NT;
    int m0 = mt*128, n0 = nt*256;

    int tid = threadIdx.x;
    int w = tid >> 6, lane = tid & 63;
    int lm = lane & 15, lq = lane >> 4;
    int wm = w >> 2, wn = w & 3;       // wave tile: rows wm*64..+64, cols wn*64..+64

    // staging (linear LDS dest, inverse-swizzled global K-chunk):
    // A: 1 call/wave, rows w*16..+15 ; B: 2 calls/wave, rows w*32..+31
    int kqs = ((lane & 3) ^ ((lane >> 3) & 3)) * 8;
    const f16* gA0 = A  + (size_t)min(m0 + w*16 + (lane >> 2), M-1)*KP + kqs;
    const f16* gB0 = Bt + (size_t)min(n0 + w*32 + (lane >> 2), NB-1)*KP + kqs;
    const f16* gB1 = Bt + (size_t)min(n0 + w*32 + 16 + (lane >> 2), NB-1)*KP + kqs;
    int sa0 = w*512;                   // A dest (f16 units) within buffer
    int sb0 = w*1024, sb1 = w*1024 + 512;

    // fragment read offsets (swizzled kq), row stride 32 f16
    int swz  = (lq ^ ((lm >> 1) & 3)) * 8;
    int aoff = (wm*64 + lm)*32 + swz;
    int boff = (wn*64 + lm)*32 + swz;

    f32x4 acc[4][4];
#pragma unroll
    for (int i = 0; i < 4; i++)
#pragma unroll
        for (int j = 0; j < 4; j++) acc[i][j] = (f32x4)0.f;

    int KT = KP >> 5;   // K-tiles of 32; >= 26 for all layers

    // prologue: stage tiles 0 and 1; drain tile0's 3 calls, keep tile1's in flight
    async_ld16(gA0,      &smem[sa0]);
    async_ld16(gB0,      &sB[sb0]);
    async_ld16(gB1,      &sB[sb1]);
    async_ld16(gA0 + 32, &smem[4096 + sa0]);
    async_ld16(gB0 + 32, &sB[8192 + sb0]);
    async_ld16(gB1 + 32, &sB[8192 + sb1]);
    asm volatile("s_waitcnt vmcnt(3)" ::: "memory");
    __builtin_amdgcn_s_barrier();

    int cur = 0, nx2 = 2;
    for (int t = 0; t < KT; t++){
        int ac = cur*4096, bc = cur*8192;
        f16x8 aF[4], bF[4];
#pragma unroll
        for (int i = 0; i < 4; i++) aF[i] = *(const f16x8*)&smem[ac + aoff + i*512];
#pragma unroll
        for (int i = 0; i < 4; i++) bF[i] = *(const f16x8*)&sB[bc + boff + i*512];
        bool s2 = (t+2 < KT);
        if (s2){
            int ko2 = (t+2)*32;
            int a2 = nx2*4096, b2 = nx2*8192;
            async_ld16(gA0 + ko2, &smem[a2 + sa0]);
            async_ld16(gB0 + ko2, &sB[b2 + sb0]);
            async_ld16(gB1 + ko2, &sB[b2 + sb1]);
        }
        __builtin_amdgcn_s_setprio(1);
#pragma unroll
        for (int i = 0; i < 4; i++)
#pragma unroll
            for (int j = 0; j < 4; j++)
                acc[i][j] = __builtin_amdgcn_mfma_f32_16x16x32_f16(aF[i], bF[j], acc[i][j], 0, 0, 0);
        __builtin_amdgcn_s_setprio(0);
        if (s2) asm volatile("s_waitcnt vmcnt(3)" ::: "memory");
        else    asm volatile("s_waitcnt vmcnt(0)" ::: "memory");
        __builtin_amdgcn_s_barrier();
        cur = (cur == 2) ? 0 : cur + 1;
        nx2 = (nx2 == 2) ? 0 : nx2 + 1;
    }

    // attention columns ([N,NB)) -> a_sd directly (registers only)
#pragma unroll
    for (int mi = 0; mi < 4; mi++){
#pragma unroll
        for (int ni = 0; ni < 4; ni++){
            int col = n0 + wn*64 + ni*16 + lm;
            if (col >= N && col < NB){
                int jc = col - N;
                int idx = (jc < H) ? jc : (3 + jc - H);
                float dv = dvec[col];
                int rbase = m0 + wm*64 + mi*16 + lq*4;
#pragma unroll
                for (int rr = 0; rr < 4; rr++){
                    int row = rbase + rr;
                    if (row < M) a_sd[(size_t)row*6 + idx] = acc[mi][ni][rr] + dv;
                }
            }
        }
    }

    // C tile (128x256) -> LDS stride 264 -> coalesced f16x8 stores
    float dv4[4];
#pragma unroll
    for (int ni = 0; ni < 4; ni++){
        int gcol = n0 + wn*64 + ni*16 + lm;
        dv4[ni] = (gcol < N) ? dvec[gcol] : 0.f;
    }
    int ncols = min(256, N - n0);
#pragma unroll
    for (int mi = 0; mi < 4; mi++){
#pragma unroll
        for (int ni = 0; ni < 4; ni++){
            int colL = wn*64 + ni*16 + lm;
#pragma unroll
            for (int rr = 0; rr < 4; rr++){
                int rowL = wm*64 + mi*16 + lq*4 + rr;
                smem[rowL*264 + colL] = (f16)(acc[mi][ni][rr] + dv4[ni]);
            }
        }
    }
    // drain LDS writes before the barrier so other waves' reads see them (race fix, round 4)
    asm volatile("s_waitcnt lgkmcnt(0)" ::: "memory");
    __builtin_amdgcn_s_barrier();
#pragma unroll
    for (int it = 0; it < 8; it++){
        int ch = tid + it*512;            // 4096 chunks: 128 rows x 32 col-chunks
        int rowL = ch >> 5, cc = (ch & 31)*8;
        int grow = m0 + rowL;
        if (grow < M && cc < ncols){
            if (cc + 8 <= ncols){
                f16x8 v = *(f16x8*)&smem[rowL*264 + cc];
                *(f16x8*)(C + (size_t)grow*SN + n0 + cc) = v;
            } else {
                for (int jj = cc; jj < ncols; jj++)
                    C[(size_t)grow*SN + n0 + jj] = smem[rowL*264 + jj];
            }
        }
    }
}

// ====== 128x128 MFMA GEMM (L2 layer): 4 waves, ring-3, 3 blocks/CU ======
// Same hazard structure as k_gemmT (4 staging calls/tile -> vmcnt(4)); fixes the
// 628-block / 512-slot tail (1099 smaller blocks -> better packing).
__global__ __launch_bounds__(256, 3) void k_gemmS(const f16* __restrict__ A,
                                                  const f16* __restrict__ Bt,
                                                  const float* __restrict__ dvec,
                                                  f16* __restrict__ C,
                                                  float* __restrict__ a_sd,
                                                  int M, int N, int NB, int H,
                                                  int KP, int SN, int Mtiles, int NT){
    __shared__ f16 smem[24576];        // A ring [0,12288): 3x4096; B ring [12288,24576): 3x4096
    f16* sB = smem + 12288;

    int nwg = Mtiles*NT;
    int bid = blockIdx.x;
    int q = nwg >> 3, r = nwg & 7, xcd = bid & 7, lin = bid >> 3;
    int wg = (xcd < r ? xcd*(q+1) : r*(q+1) + (xcd - r)*q) + lin;
    int mt = wg / NT, nt = wg - mt*NT;
    int m0 = mt*128, n0 = nt*128;

    int tid = threadIdx.x;
    int w = tid >> 6, lane = tid & 63;      // 4 waves
    int lm = lane & 15, lq = lane >> 4;
    int wm = w >> 1, wn = w & 1;            // wave tile 64x64: rows wm*64.., cols wn*64..

    // staging: A rows 128: wave w rows w*32..+31 (2 calls); B same.
    int kqs = ((lane & 3) ^ ((lane >> 3) & 3)) * 8;
    const f16* gA0 = A  + (size_t)min(m0 + w*32 + (lane >> 2), M-1)*KP + kqs;
    const f16* gA1 = A  + (size_t)min(m0 + w*32 + 16 + (lane >> 2), M-1)*KP + kqs;
    const f16* gB0 = Bt + (size_t)min(n0 + w*32 + (lane >> 2), NB-1)*KP + kqs;
    const f16* gB1 = Bt + (size_t)min(n0 + w*32 + 16 + (lane >> 2), NB-1)*KP + kqs;
    int sa0 = w*1024, sa1 = w*1024 + 512;
    int sb0 = w*1024, sb1 = w*1024 + 512;

    int swz  = (lq ^ ((lm >> 1) & 3)) * 8;
    int aoff = (wm*64 + lm)*32 + swz;
    int boff = (wn*64 + lm)*32 + swz;

    f32x4 acc[4][4];
#pragma unroll
    for (int i = 0; i < 4; i++)
#pragma unroll
        for (int j = 0; j < 4; j++) acc[i][j] = (f32x4)0.f;

    int KT = KP >> 5;

    // prologue: tiles 0 and 1 (4 calls each); drain tile0, keep tile1 in flight
    async_ld16(gA0,      &smem[sa0]);        async_ld16(gA1,      &smem[sa1]);
    async_ld16(gB0,      &sB[sb0]);          async_ld16(gB1,      &sB[sb1]);
    async_ld16(gA0 + 32, &smem[4096 + sa0]); async_ld16(gA1 + 32, &smem[4096 + sa1]);
    async_ld16(gB0 + 32, &sB[4096 + sb0]);   async_ld16(gB1 + 32, &sB[4096 + sb1]);
    asm volatile("s_waitcnt vmcnt(4)" ::: "memory");
    __builtin_amdgcn_s_barrier();

    int cur = 0, nx2 = 2;
    for (int t = 0; t < KT; t++){
        int ac = cur*4096, bc = cur*4096;
        f16x8 aF[4], bF[4];
#pragma unroll
        for (int i = 0; i < 4; i++) aF[i] = *(const f16x8*)&smem[ac + aoff + i*512];
#pragma unroll
        for (int i = 0; i < 4; i++) bF[i] = *(const f16x8*)&sB[bc + boff + i*512];
        bool s2 = (t+2 < KT);
        if (s2){
            int ko2 = (t+2)*32;
            int a2 = nx2*4096, b2 = nx2*4096;
            async_ld16(gA0 + ko2, &smem[a2 + sa0]); async_ld16(gA1 + ko2, &smem[a2 + sa1]);
            async_ld16(gB0 + ko2, &sB[b2 + sb0]);   async_ld16(gB1 + ko2, &sB[b2 + sb1]);
        }
        __builtin_amdgcn_s_setprio(1);
#pragma unroll
        for (int i = 0; i < 4; i++)
#pragma unroll
            for (int j = 0; j < 4; j++)
                acc[i][j] = __builtin_amdgcn_mfma_f32_16x16x32_f16(aF[i], bF[j], acc[i][j], 0, 0, 0);
        __builtin_amdgcn_s_setprio(0);
        if (s2) asm volatile("s_waitcnt vmcnt(4)" ::: "memory");
        else    asm volatile("s_waitcnt vmcnt(0)" ::: "memory");
        __builtin_amdgcn_s_barrier();
        cur = (cur == 2) ? 0 : cur + 1;
        nx2 = (nx2 == 2) ? 0 : nx2 + 1;
    }

    // attention columns
#pragma unroll
    for (int mi = 0; mi < 4; mi++){
#pragma unroll
        for (int ni = 0; ni < 4; ni++){
            int col = n0 + wn*64 + ni*16 + lm;
            if (col >= N && col < NB){
                int jc = col - N;
                int idx = (jc < H) ? jc : (3 + jc - H);
                float dv = dvec[col];
                int rbase = m0 + wm*64 + mi*16 + lq*4;
#pragma unroll
                for (int rr = 0; rr < 4; rr++){
                    int row = rbase + rr;
                    if (row < M) a_sd[(size_t)row*6 + idx] = acc[mi][ni][rr] + dv;
                }
            }
        }
    }

    // C tile (128x128) -> LDS stride 136 -> coalesced stores
    float dv4[4];
#pragma unroll
    for (int ni = 0; ni < 4; ni++){
        int gcol = n0 + wn*64 + ni*16 + lm;
        dv4[ni] = (gcol < N) ? dvec[gcol] : 0.f;
    }
    int ncols = min(128, N - n0);
#pragma unroll
    for (int mi = 0; mi < 4; mi++){
#pragma unroll
        for (int ni = 0; ni < 4; ni++){
            int colL = wn*64 + ni*16 + lm;
#pragma unroll
            for (int rr = 0; rr < 4; rr++){
                int rowL = wm*64 + mi*16 + lq*4 + rr;
                smem[rowL*136 + colL] = (f16)(acc[mi][ni][rr] + dv4[ni]);
            }
        }
    }
    asm volatile("s_waitcnt lgkmcnt(0)" ::: "memory");
    __builtin_amdgcn_s_barrier();
#pragma unroll
    for (int it = 0; it < 8; it++){
        int ch = tid + it*256;            // 2048 chunks: 128 rows x 16 col-chunks
        int rowL = ch >> 4, cc = (ch & 15)*8;
        int grow = m0 + rowL;
        if (grow < M && cc < ncols){
            if (cc + 8 <= ncols){
                f16x8 v = *(f16x8*)&smem[rowL*136 + cc];
                *(f16x8*)(C + (size_t)grow*SN + n0 + cc) = v;
            } else {
                for (int jj = cc; jj < ncols; jj++)
                    C[(size_t)grow*SN + n0 + jj] = smem[rowL*136 + jj];
            }
        }
    }
}

// ---- phase 1: per-node softmax -> per-edge alpha (f32) ----
template<int H>
__global__ __launch_bounds__(256) void k_alpha(const int* __restrict__ rp, const int* __restrict__ csrc,
                                               const float* __restrict__ a_sd, float* __restrict__ alpha){
    int n = blockIdx.x*4 + (threadIdx.x >> 6);
    if (n >= NN) return;
    int lane = threadIdx.x & 63;
    int beg = rp[n], deg = rp[n+1] - beg;

    float adv[H];
#pragma unroll
    for (int h = 0; h < H; h++) adv[h] = a_sd[(size_t)n*6 + 3 + h];

    bool act0 = lane < deg;
    int sl0 = 0; float t0[H];
    if (act0){
        sl0 = csrc[beg + lane];
#pragma unroll
        for (int h = 0; h < H; h++){
            float t = a_sd[(size_t)sl0*6 + h] + adv[h];
            t0[h] = t > 0.f ? t : 0.2f*t;
        }
    } else {
#pragma unroll
        for (int h = 0; h < H; h++) t0[h] = -1e30f;
    }

    float mx[H];
#pragma unroll
    for (int h = 0; h < H; h++) mx[h] = t0[h];
    for (int base = 64; base < deg; base += 64){
        int e = base + lane;
        if (e < deg){
            int s = csrc[beg + e];
#pragma unroll
            for (int h = 0; h < H; h++){
                float t = a_sd[(size_t)s*6 + h] + adv[h];
                t = t > 0.f ? t : 0.2f*t;
                mx[h] = fmaxf(mx[h], t);
            }
        }
    }
#pragma unroll
    for (int off = 32; off; off >>= 1)
#pragma unroll
        for (int h = 0; h < H; h++) mx[h] = fmaxf(mx[h], __shfl_xor(mx[h], off));

    float dn[H];
#pragma unroll
    for (int h = 0; h < H; h++) dn[h] = act0 ? expf(t0[h] - mx[h]) : 0.f;
    for (int base = 64; base < deg; base += 64){
        int e = base + lane;
        if (e < deg){
            int s = csrc[beg + e];
#pragma unroll
            for (int h = 0; h < H; h++){
                float t = a_sd[(size_t)s*6 + h] + adv[h];
                t = t > 0.f ? t : 0.2f*t;
                dn[h] += expf(t - mx[h]);
            }
        }
    }
#pragma unroll
    for (int off = 32; off; off >>= 1)
#pragma unroll
        for (int h = 0; h < H; h++) dn[h] += __shfl_xor(dn[h], off);
    float inv[H];
#pragma unroll
    for (int h = 0; h < H; h++) inv[h] = 1.f / (dn[h] + 1e-16f);

    if (act0){
        if (H == 3){
            float4 o;
            o.x = expf(t0[0]-mx[0])*inv[0];
            o.y = expf(t0[1]-mx[1])*inv[1];
            o.z = expf(t0[2]-mx[2])*inv[2];
            o.w = 0.f;
            *(float4*)(alpha + (size_t)(beg+lane)*4) = o;
        } else {
            alpha[beg+lane] = expf(t0[0]-mx[0])*inv[0];
        }
    }
    for (int base = 64; base < deg; base += 64){
        int e = base + lane;
        if (e < deg){
            int s = csrc[beg + e];
            float av[H];
#pragma unroll
            for (int h = 0; h < H; h++){
                float t = a_sd[(size_t)s*6 + h] + adv[h];
                t = t > 0.f ? t : 0.2f*t;
                av[h] = expf(t - mx[h]) * inv[h];
            }
            if (H == 3){
                float4 o; o.x = av[0]; o.y = av[1]; o.z = av[2]; o.w = 0.f;
                *(float4*)(alpha + (size_t)(beg+e)*4) = o;
            } else {
                alpha[beg+e] = av[0];
            }
        }
    }
}

// ---- phase 2: gather. Wave-per-(node, 512-col group) (best measured form, round 6) ----
template<int H>
__global__ __launch_bounds__(256) void k_gather(const f16* __restrict__ hp, const int* __restrict__ rp,
                                                const int* __restrict__ csrc, const float* __restrict__ alpha,
                                                const float* __restrict__ bias, f16* __restrict__ y,
                                                int SP, int W){
    int w = threadIdx.x >> 6, lane = threadIdx.x & 63;
    int n = blockIdx.x*4 + w;
    if (n >= NN) return;
    int c = blockIdx.y*512 + lane*8;
    bool cok = c < SP;
    int beg = rp[n], deg = rp[n+1] - beg;

    int hl = 0, hh = 0, nsp = 8;
    if (H == 3){
        hl = min(c/EMB, 2); hh = min((c+7)/EMB, 2);
        nsp = (hh > hl) ? (EMB*(hl+1) - c) : 8;
    }
    float acc[8];
#pragma unroll
    for (int j = 0; j < 8; j++) acc[j] = 0.f;

    for (int base = 0; base < deg; base += 64){
        int cnt = min(64, deg - base);
        int e0 = base + lane;
        int sl = 0; float a0v = 0.f, a1v = 0.f, a2v = 0.f;
        if (e0 < deg){
            sl = csrc[beg + e0];
            if (H == 3){
                float4 al4 = *(const float4*)(alpha + (size_t)(beg+e0)*4);
                a0v = al4.x; a1v = al4.y; a2v = al4.z;
            } else {
                a0v = alpha[beg + e0];
            }
        }
#pragma unroll 4
        for (int e = 0; e < cnt; e++){
            int s = __shfl(sl, e);
            float b0 = __shfl(a0v, e);
            float b1 = (H==3) ? __shfl(a1v, e) : b0;
            float b2 = (H==3) ? __shfl(a2v, e) : b0;
            if (cok){
                f16x8 v = *(const f16x8*)(hp + (size_t)s*SP + c);
                float lo = (H==3) ? ((hl==0)?b0:((hl==1)?b1:b2)) : b0;
                float hi = (H==3) ? ((hh==0)?b0:((hh==1)?b1:b2)) : b0;
#pragma unroll
                for (int j = 0; j < 8; j++)
                    acc[j] += ((j < nsp) ? lo : hi) * (float)v[j];
            }
        }
    }

    if (cok){
        f16x8 o;
#pragma unroll
        for (int j = 0; j < 8; j++){
            float vv = (c + j < W) ? tanhf(acc[j] + bias[c+j]) : 0.f;
            o[j] = (f16)vv;
        }
        *(f16x8*)(y + (size_t)n*SP + c) = o;
    }
}

// ---------------- BatchNorm stats: contiguous-row-range partials (no atomics) ----------------
__global__ void k_bnstat(const f16* __restrict__ y, float* __restrict__ ps,
                         float* __restrict__ pq, int W, int SP){
    int c0 = (blockIdx.x*256 + threadIdx.x)*4;
    if (c0 >= W) return;
    int slice = blockIdx.y;   // 0..127
    int r0 = (int)(((long long)NN*slice)/128);
    int r1 = (int)(((long long)NN*(slice+1))/128);
    float s[4] = {0,0,0,0}, q[4] = {0,0,0,0};
    for (int r = r0; r < r1; r++){
        f16x4 u = *(const f16x4*)(y + (size_t)r*SP + c0);
#pragma unroll
        for (int j = 0; j < 4; j++){ float v = (float)u[j]; s[j] += v; q[j] += v*v; }
    }
#pragma unroll
    for (int j = 0; j < 4; j++){
        ps[(size_t)slice*W3 + c0+j] = s[j];
        pq[(size_t)slice*W3 + c0+j] = q[j];
    }
}

// reduce partials; sc = istd*gamma, sh = beta - mu*istd*gamma; zero dvec for next layer
__global__ void k_bnfin(const float* __restrict__ ps, const float* __restrict__ pq,
                        const float* __restrict__ gamma, const float* __restrict__ beta,
                        float* __restrict__ sc, float* __restrict__ sh,
                        float* __restrict__ dvec, int W, int zn){
    int c = blockIdx.x*256 + threadIdx.x;
    if (c < W){
        float m = 0.f, q = 0.f;
        for (int s = 0; s < 128; s++){ m += ps[(size_t)s*W3 + c]; q += pq[(size_t)s*W3 + c]; }
        m *= (1.f/NN);
        float v = q * (1.f/NN) - m*m;
        float is = 1.f / sqrtf(v + 1e-5f);
        float g = gamma[c];
        sc[c] = is * g;
        sh[c] = beta[c] - m * is * g;
    }
    if (c < zn) dvec[c] = 0.f;
}

// ---------------- segmented pooling (raw y; BN folded into MLP) ----------------
__global__ void k_pool(const f16* __restrict__ h, const int* __restrict__ grp,
                       float* __restrict__ pooled){
    int g = blockIdx.x;
    int c = threadIdx.x*4;
    if (c >= EMB) return;
    int r0 = grp[g], r1 = grp[g+1];
    float s0=0.f, s1=0.f, s2=0.f, s3=0.f;
    for (int r = r0; r < r1; r++){
        f16x4 u = *(const f16x4*)(h + (size_t)r*EMBP + c);
        s0 += (float)u[0]; s1 += (float)u[1]; s2 += (float)u[2]; s3 += (float)u[3];
    }
    pooled[g*EMB + c] = s0; pooled[g*EMB + c+1] = s1;
    pooled[g*EMB + c+2] = s2; pooled[g*EMB + c+3] = s3;
}

__global__ __launch_bounds__(256) void k_mlp(const float* __restrict__ pooled, const int* __restrict__ grp,
                                             const float* __restrict__ sc, const float* __restrict__ sh,
                                             const float* __restrict__ W1, const float* __restrict__ b1,
                                             const float* __restrict__ W2, const float* __restrict__ b2,
                                             float* __restrict__ out){
    __shared__ float p[EMB];
    __shared__ float hid[128];
    int g = blockIdx.x, tid = threadIdx.x;
    int cnt = grp[g+1] - grp[g];
    float ic = 1.f / fmaxf((float)cnt, 1.f);
    for (int c = tid; c < EMB; c += 256){
        float v = pooled[g*EMB + c] * ic * sc[c] + sh[c];   // BN(mean) — affine commutes with mean
        p[c] = v > 0.f ? v : 0.f;
    }
    __syncthreads();
    if (tid < 128){
        float s = b1[tid];
        for (int k = 0; k < EMB; k++) s += p[k] * W1[k*128 + tid];
        hid[tid] = tanhf(s);
    }
    __syncthreads();
    if (tid < 64){
        float s = b2[tid];
        for (int k = 0; k < 128; k++) s += hid[k] * W2[k*64 + tid];
        out[g*64 + tid] = s;
    }
}

// ---------------- launch ----------------
extern "C" void kernel_launch(void* const* d_in, const int* in_sizes, int n_in,
                              void* d_out, int out_size, void* d_ws, size_t ws_size,
                              hipStream_t stream) {
    (void)in_sizes; (void)n_in; (void)out_size;
    const float* x    = (const float*)d_in[0];
    const int*   ei   = (const int*)  d_in[1];
    const int*   batch= (const int*)  d_in[2];
    const float* tW   = (const float*)d_in[3];
    const float* tb   = (const float*)d_in[4];
    const float* W0   = (const float*)d_in[5];
    const float* as0  = (const float*)d_in[6];
    const float* ad0  = (const float*)d_in[7];
    const float* b0   = (const float*)d_in[8];
    const float* g0   = (const float*)d_in[9];
    const float* be0  = (const float*)d_in[10];
    const float* W1   = (const float*)d_in[11];
    const float* as1  = (const float*)d_in[12];
    const float* ad1  = (const float*)d_in[13];
    const float* b1   = (const float*)d_in[14];
    const float* g1   = (const float*)d_in[15];
    const float* be1  = (const float*)d_in[16];
    const float* W2   = (const float*)d_in[17];
    const float* as2  = (const float*)d_in[18];
    const float* ad2  = (const float*)d_in[19];
    const float* b2   = (const float*)d_in[20];
    const float* g2   = (const float*)d_in[21];
    const float* be2  = (const float*)d_in[22];
    const float* mW1  = (const float*)d_in[23];
    const float* mb1  = (const float*)d_in[24];
    const float* mW2  = (const float*)d_in[25];
    const float* mb2  = (const float*)d_in[26];
    float* outp = (float*)d_out;

    size_t off = 0;
    auto carve = [&](size_t bytes) -> void* {
        void* p = (char*)d_ws + off;
        off = (off + bytes + 255) & ~(size_t)255;
        return p;
    };
    f16* big1 = (f16*)carve((size_t)NN*W3P*2);          // h / y buffers
    f16* big2 = (f16*)carve((size_t)NN*W3P*2);          // hp buffer
    f16* Wt   = (f16*)carve((size_t)NZ*W3P*2);          // transposed weights + attention rows
    float* a_sd  = (float*)carve((size_t)NN*6*4);       // [n][a_s(3), a_d(3)]
    float* psum  = (float*)carve((size_t)128*W3*4);     // bnstat partials
    float* psq   = (float*)carve((size_t)128*W3*4);
    float* sc    = (float*)carve((size_t)W3*4);
    float* sh    = (float*)carve((size_t)W3*4);
    float* dvec  = (float*)carve((size_t)NZ*4);
    float* alphab= (float*)carve((size_t)ELP*4*4);      // per-edge softmax weights (float4/H=3)
    float* pooled= (float*)carve((size_t)NGR*EMB*4);
    int*   grp   = (int*)carve((size_t)(NGR+1)*4);
    int*   deg   = (int*)carve((size_t)NN*4);           // reused as cursor
    int*   rp    = (int*)carve((size_t)(NN+1)*4);
    int*   csrc  = (int*)carve((size_t)ELP*4);

    if (ws_size < off) return;

    // CSR build
    k_zero_i32<<<cdiv_i(NN,256),256,0,stream>>>(deg, NN);
    k_deg<<<cdiv_i(ELP,256),256,0,stream>>>(ei, deg);
    k_scan<<<1,1024,0,stream>>>(deg, rp);
    k_fill<<<cdiv_i(ELP,256),256,0,stream>>>(ei, deg, csrc);
    k_grp<<<1,256,0,stream>>>(batch, grp);

    // h0 + initial dvec zero (layer 0 has no BN fold)
    k_build_h<<<cdiv_i((long long)NN*(EMBP/4),256),256,0,stream>>>(x, tW, tb, big1);
    k_zero_f32<<<cdiv_i(NZ,256),256,0,stream>>>(dvec, NZ);

    struct Layer { const float* W; const float* as; const float* ad; const float* b;
                   const float* g; const float* be; int H; int K; int KP; };
    Layer layers[3] = {
        {W0, as0, ad0, b0, g0, be0, 3, EMB, EMBP},
        {W1, as1, ad1, b1, g1, be1, 3, W3,  W3P },
        {W2, as2, ad2, b2, g2, be2, 1, W3,  W3P },
    };

    for (int L = 0; L < 3; L++){
        Layer& ly = layers[L];
        int Wout  = ly.H * EMB;                 // 2340 / 2340 / 780
        int NB    = Wout + 2*ly.H;              // + attention columns
        int SPout = (Wout == W3) ? W3P : EMBP;  // 2368 / 2368 / 832
        const float* scale = (L == 0) ? nullptr : sc;
        const float* shift = (L == 0) ? nullptr : sh;

        // Wt rows [0,Wout): scaled W^T (+ fused dvec accumulation); rows [Wout,NB): att fold
        dim3 tg(cdiv_i(Wout,32), cdiv_i(ly.KP,32));
        k_transpose<<<tg, dim3(32,8), 0, stream>>>(ly.W, Wt, scale, shift, dvec, ly.K, Wout, ly.KP);
        k_wvec<<<cdiv_i(ly.K,4),256,0,stream>>>(ly.W, ly.as, ly.ad, scale, Wt, dvec, ly.K, Wout, ly.KP, ly.H);

        // hp (+ a_s/a_d) = BN(h) @ [W | w_att]
        if (L < 2){
            int Mtiles = cdiv_i(NN,128), NT = cdiv_i(NB,256);
            k_gemmT<<<Mtiles*NT, 512, 0, stream>>>(big1, Wt, dvec, big2, a_sd,
                                                   NN, Wout, NB, ly.H, ly.KP, SPout, Mtiles, NT);
        } else {
            int Mtiles = cdiv_i(NN,128), NT = cdiv_i(NB,128);
            k_gemmS<<<Mtiles*NT, 256, 0, stream>>>(big1, Wt, dvec, big2, a_sd,
                                                   NN, Wout, NB, ly.H, ly.KP, SPout, Mtiles, NT);
        }

        // softmax -> per-edge alpha, then wave-per-(node,colgroup) gather + bias + tanh
        dim3 gg(cdiv_i(NN,4), cdiv_i(SPout,512));
        if (ly.H == 3){
            k_alpha<3><<<cdiv_i(NN,4),256,0,stream>>>(rp, csrc, a_sd, alphab);
            k_gather<3><<<gg,256,0,stream>>>(big2, rp, csrc, alphab, ly.b, big1, SPout, Wout);
        } else {
            k_alpha<1><<<cdiv_i(NN,4),256,0,stream>>>(rp, csrc, a_sd, alphab);
            k_gather<1><<<gg,256,0,stream>>>(big2, rp, csrc, alphab, ly.b, big1, SPout, Wout);
        }

        // BN stats + fold coefficients (+ zero dvec for next layer)
        dim3 gs(cdiv_i(Wout/4,256), 128);
        k_bnstat<<<gs,256,0,stream>>>(big1, psum, psq, Wout, SPout);
        int zn = (L < 2) ? NZ : 0;
        k_bnfin<<<cdiv_i(Wout,256),256,0,stream>>>(psum, psq, ly.g, ly.be, sc, sh, dvec, Wout, zn);
    }

    // segmented pooling (raw y) + MLP (applies final BN affine on pooled means)
    k_pool<<<NGR,256,0,stream>>>(big1, grp, pooled);
    k_mlp<<<NGR,256,0,stream>>>(pooled, grp, sc, sh, mW1, mb1, mW2, mb2, outp);
}

// Round 10
// 1382.382 us; speedup vs baseline: 1.0715x; 1.0116x over previous
//
#include <hip/hip_runtime.h>
#include <math.h>

#define NN   20000
#define EE   80000
#define ELP  100000   // EE + NN self loops
#define NGR  64
#define EMB  780
#define W3   2340
#define EMBP 832      // 780 padded to mult of 64
#define W3P  2368     // 2340 padded to mult of 64
#define NZ   (W3+8)   // dvec length (incl. attention-correction slots)
#define KPA  800      // agg K-stride (780 padded to mult of 32)

static inline int cdiv_i(long long a, long long b){ return (int)((a + b - 1) / b); }

typedef _Float16 f16;
typedef _Float16 f16x4 __attribute__((ext_vector_type(4)));
typedef _Float16 f16x8 __attribute__((ext_vector_type(8)));
typedef float    f32x4 __attribute__((ext_vector_type(4)));

__device__ __forceinline__ void async_ld16(const f16* g, f16* l){
    __builtin_amdgcn_global_load_lds(
        (const __attribute__((address_space(1))) unsigned int*)g,
        (__attribute__((address_space(3))) unsigned int*)l,
        16, 0, 0);
}

// ---------------- utility kernels ----------------
__global__ void k_zero_f32(float* p, int n){
    int i = blockIdx.x*256 + threadIdx.x; if (i < n) p[i] = 0.f;
}
__global__ void k_zero_i32(int* p, int n){
    int i = blockIdx.x*256 + threadIdx.x; if (i < n) p[i] = 0;
}
// zero pad cols [W3, W3P) of y (after L0 head-GEMMs which write only [0,W3))
__global__ void k_padzero(f16* y){
    int i = blockIdx.x*256 + threadIdx.x;   // NN * 7 f16x4 chunks
    if (i >= NN*7) return;
    int rw = i / 7, c = W3 + (i - rw*7)*4;
    f16x4 z; z[0]=(f16)0.f; z[1]=(f16)0.f; z[2]=(f16)0.f; z[3]=(f16)0.f;
    *(f16x4*)(y + (size_t)rw*W3P + c) = z;
}

// W [K,N] fp32 -> Wt [N,KP] f16 (scaled by sc for BN fold); also accumulates
// dvec[n] += sum_k sh[k]*W[k,n] (RAW W) via per-tile reduction + 32 atomics.
__global__ void k_transpose(const float* __restrict__ W, f16* __restrict__ Wt,
                            const float* __restrict__ sc, const float* __restrict__ sh,
                            float* __restrict__ dvec, int K, int N, int KP){
    __shared__ float T[32][33];
    __shared__ float D[8][33];
    int n0 = blockIdx.x*32, k0 = blockIdx.y*32;
    int tx = threadIdx.x, ty = threadIdx.y;   // 32 x 8
    float raw[4];
#pragma unroll
    for (int r = 0; r < 4; r++){
        int k = k0 + ty + r*8;
        float w = 0.f;
        if (k < K && n0 + tx < N) w = W[(size_t)k*N + n0 + tx];
        raw[r] = w;
        T[ty + r*8][tx] = sc ? w * ((k < K) ? sc[k] : 0.f) : w;
    }
    if (sh){
        float p = 0.f;
#pragma unroll
        for (int r = 0; r < 4; r++){
            int k = k0 + ty + r*8;
            if (k < K) p += sh[k] * raw[r];
        }
        D[ty][tx] = p;
    }
    __syncthreads();
#pragma unroll
    for (int r = 0; r < 4; r++){
        int n = n0 + ty + r*8;
        int k = k0 + tx;
        if (n < N && k < KP) Wt[(size_t)n*KP + k] = (f16)T[tx][ty + r*8];
    }
    if (sh && ty == 0 && n0 + tx < N){
        float s = 0.f;
#pragma unroll
        for (int j = 0; j < 8; j++) s += D[j][tx];
        atomicAdd(&dvec[n0 + tx], s);
    }
}

// Attention fold: Wt[N+i][k] = sc[k] * sum_c W[k, h*EMB+c] * att[i][c]
// block 0 additionally computes dvec[N+i] (rank-1 correction), dvec core already final.
__global__ void k_wvec(const float* __restrict__ W, const float* __restrict__ asrc,
                       const float* __restrict__ adst, const float* __restrict__ sc,
                       f16* __restrict__ Wt, float* __restrict__ dvec,
                       int K, int N, int KP, int H){
    int k = blockIdx.x*4 + (threadIdx.x >> 6);
    int lane = threadIdx.x & 63;
    if (k < K){
        const float* row = W + (size_t)k*N;
        float acc[6];
#pragma unroll
        for (int i = 0; i < 6; i++) acc[i] = 0.f;
        for (int c = lane; c < EMB; c += 64){
            for (int h = 0; h < H; h++){
                float wv = row[h*EMB + c];
                acc[h]     += wv * asrc[h*EMB + c];
                acc[H + h] += wv * adst[h*EMB + c];
            }
        }
        float s = sc ? sc[k] : 1.f;
        for (int i = 0; i < 2*H; i++){
            float v = acc[i];
#pragma unroll
            for (int off = 32; off; off >>= 1) v += __shfl_xor(v, off);
            if (lane == 0) Wt[(size_t)(N + i)*KP + k] = (f16)(v * s);
        }
    }
    if (blockIdx.x == 0){
        int wv = threadIdx.x >> 6;
        for (int i = wv; i < 2*H; i += 4){
            int h = (i < H) ? i : (i - H);
            const float* att = (i < H) ? (asrc + h*EMB) : (adst + h*EMB);
            float s = 0.f;
            for (int c = lane; c < EMB; c += 64) s += dvec[h*EMB + c] * att[c];
#pragma unroll
            for (int off = 32; off; off >>= 1) s += __shfl_xor(s, off);
            if (lane == 0) dvec[N + i] = s;
        }
    }
}

// ---------------- h0 (f16x4 stores) ----------------
__global__ void k_build_h(const float* __restrict__ x, const float* __restrict__ tW,
                          const float* __restrict__ tb, f16* __restrict__ h){
    int idx = blockIdx.x*256 + threadIdx.x;
    int total = NN*(EMBP/4);
    if (idx >= total) return;
    int n = idx / (EMBP/4);
    int c0 = (idx - n*(EMBP/4))*4;
    const float* xr = x + (size_t)n*772;
    f16x4 o;
#pragma unroll
    for (int j = 0; j < 4; j++){
        int c = c0 + j; float v;
        if (c < 768) v = xr[c];
        else if (c < EMB){
            int t = c - 768;
            v = tb[t] + xr[768]*tW[t] + xr[769]*tW[12+t] + xr[770]*tW[24+t] + xr[771]*tW[36+t];
        } else v = 0.f;
        o[j] = (f16)v;
    }
    *(f16x4*)(h + (size_t)n*EMBP + c0) = o;
}

// ---------------- CSR build ----------------
__global__ void k_deg(const int* __restrict__ ei, int* __restrict__ deg){
    int k = blockIdx.x*256 + threadIdx.x; if (k >= ELP) return;
    int d = (k < EE) ? ei[EE + k] : (k - EE);
    atomicAdd(&deg[d], 1);
}

// 20 nodes/thread local sum -> single 1024-scan -> write prefixes into rp AND cursor(deg, in place)
__global__ __launch_bounds__(1024) void k_scan(int* __restrict__ deg, int* __restrict__ rp){
    __shared__ int part[1024];
    int tid = threadIdx.x;
    int i0 = tid*20;
    int n = (i0 < NN) ? min(20, NN - i0) : 0;
    int s = 0;
    for (int k = 0; k < n; k++) s += deg[i0+k];
    part[tid] = s; __syncthreads();
    for (int off = 1; off < 1024; off <<= 1){
        int t = (tid >= off) ? part[tid-off] : 0;
        __syncthreads();
        part[tid] += t;
        __syncthreads();
    }
    int run = part[tid] - s;   // exclusive prefix
    for (int k = 0; k < n; k++){
        int d = deg[i0+k];
        rp[i0+k] = run;
        deg[i0+k] = run;       // cursor init
        run += d;
    }
    if (tid == 1023) rp[NN] = part[1023];
}

__global__ void k_fill(const int* __restrict__ ei, int* __restrict__ cursor, int* __restrict__ csrc){
    int k = blockIdx.x*256 + threadIdx.x; if (k >= ELP) return;
    int s, d;
    if (k < EE){ s = ei[k]; d = ei[EE + k]; } else { s = k - EE; d = s; }
    int pos = atomicAdd(&cursor[d], 1);
    csrc[pos] = s;
}

__global__ void k_grp(const int* __restrict__ batch, int* __restrict__ grp){
    int g = blockIdx.x*256 + threadIdx.x; if (g > NGR) return;
    int lo = 0, hi = NN;
    while (lo < hi){ int mid = (lo+hi)>>1; if (batch[mid] < g) lo = mid+1; else hi = mid; }
    grp[g] = lo;
}

// ====== 128x256 MFMA GEMM, BK=32, ring-3 LDS, 2 blocks/CU (verified round 4) ======
__global__ __launch_bounds__(512, 4) void k_gemmT(const f16* __restrict__ A,
                                                  const f16* __restrict__ Bt,
                                                  const float* __restrict__ dvec,
                                                  f16* __restrict__ C,
                                                  float* __restrict__ a_sd,
                                                  int M, int N, int NB, int H,
                                                  int KP, int SN, int Mtiles, int NT){
    __shared__ f16 smem[36864];        // A ring [0,12288): 3x4096; B ring [12288,36864): 3x8192
    f16* sB = smem + 12288;

    // bijective XCD-chunked swizzle, mt-major: one XCD works a contiguous M strip (A L2 reuse)
    int nwg = Mtiles*NT;
    int bid = blockIdx.x;
    int q = nwg >> 3, r = nwg & 7, xcd = bid & 7, lin = bid >> 3;
    int wg = (xcd < r ? xcd*(q+1) : r*(q+1) + (xcd - r)*q) + lin;
    int mt = wg / NT, nt = wg - mt*NT;
    int m0 = mt*128, n0 = nt*256;

    int tid = threadIdx.x;
    int w = tid >> 6, lane = tid & 63;
    int lm = lane & 15, lq = lane >> 4;
    int wm = w >> 2, wn = w & 3;       // wave tile: rows wm*64..+64, cols wn*64..+64

    // staging (linear LDS dest, inverse-swizzled global K-chunk):
    int kqs = ((lane & 3) ^ ((lane >> 3) & 3)) * 8;
    const f16* gA0 = A  + (size_t)min(m0 + w*16 + (lane >> 2), M-1)*KP + kqs;
    const f16* gB0 = Bt + (size_t)min(n0 + w*32 + (lane >> 2), NB-1)*KP + kqs;
    const f16* gB1 = Bt + (size_t)min(n0 + w*32 + 16 + (lane >> 2), NB-1)*KP + kqs;
    int sa0 = w*512;                   // A dest (f16 units) within buffer
    int sb0 = w*1024, sb1 = w*1024 + 512;

    // fragment read offsets (swizzled kq), row stride 32 f16
    int swz  = (lq ^ ((lm >> 1) & 3)) * 8;
    int aoff = (wm*64 + lm)*32 + swz;
    int boff = (wn*64 + lm)*32 + swz;

    f32x4 acc[4][4];
#pragma unroll
    for (int i = 0; i < 4; i++)
#pragma unroll
        for (int j = 0; j < 4; j++) acc[i][j] = (f32x4)0.f;

    int KT = KP >> 5;

    // prologue: stage tiles 0 and 1; drain tile0's 3 calls, keep tile1's in flight
    async_ld16(gA0,      &smem[sa0]);
    async_ld16(gB0,      &sB[sb0]);
    async_ld16(gB1,      &sB[sb1]);
    async_ld16(gA0 + 32, &smem[4096 + sa0]);
    async_ld16(gB0 + 32, &sB[8192 + sb0]);
    async_ld16(gB1 + 32, &sB[8192 + sb1]);
    asm volatile("s_waitcnt vmcnt(3)" ::: "memory");
    __builtin_amdgcn_s_barrier();

    int cur = 0, nx2 = 2;
    for (int t = 0; t < KT; t++){
        int ac = cur*4096, bc = cur*8192;
        f16x8 aF[4], bF[4];
#pragma unroll
        for (int i = 0; i < 4; i++) aF[i] = *(const f16x8*)&smem[ac + aoff + i*512];
#pragma unroll
        for (int i = 0; i < 4; i++) bF[i] = *(const f16x8*)&sB[bc + boff + i*512];
        bool s2 = (t+2 < KT);
        if (s2){
            int ko2 = (t+2)*32;
            int a2 = nx2*4096, b2 = nx2*8192;
            async_ld16(gA0 + ko2, &smem[a2 + sa0]);
            async_ld16(gB0 + ko2, &sB[b2 + sb0]);
            async_ld16(gB1 + ko2, &sB[b2 + sb1]);
        }
        __builtin_amdgcn_s_setprio(1);
#pragma unroll
        for (int i = 0; i < 4; i++)
#pragma unroll
            for (int j = 0; j < 4; j++)
                acc[i][j] = __builtin_amdgcn_mfma_f32_16x16x32_f16(aF[i], bF[j], acc[i][j], 0, 0, 0);
        __builtin_amdgcn_s_setprio(0);
        if (s2) asm volatile("s_waitcnt vmcnt(3)" ::: "memory");
        else    asm volatile("s_waitcnt vmcnt(0)" ::: "memory");
        __builtin_amdgcn_s_barrier();
        cur = (cur == 2) ? 0 : cur + 1;
        nx2 = (nx2 == 2) ? 0 : nx2 + 1;
    }

    // attention columns ([N,NB)) -> a_sd directly (registers only)
#pragma unroll
    for (int mi = 0; mi < 4; mi++){
#pragma unroll
        for (int ni = 0; ni < 4; ni++){
            int col = n0 + wn*64 + ni*16 + lm;
            if (col >= N && col < NB){
                int jc = col - N;
                int idx = (jc < H) ? jc : (3 + jc - H);
                float dv = dvec[col];
                int rbase = m0 + wm*64 + mi*16 + lq*4;
#pragma unroll
                for (int rr = 0; rr < 4; rr++){
                    int row = rbase + rr;
                    if (row < M) a_sd[(size_t)row*6 + idx] = acc[mi][ni][rr] + dv;
                }
            }
        }
    }

    // C tile (128x256) -> LDS stride 264 -> coalesced f16x8 stores
    float dv4[4];
#pragma unroll
    for (int ni = 0; ni < 4; ni++){
        int gcol = n0 + wn*64 + ni*16 + lm;
        dv4[ni] = (gcol < N) ? dvec[gcol] : 0.f;
    }
    int ncols = min(256, N - n0);
#pragma unroll
    for (int mi = 0; mi < 4; mi++){
#pragma unroll
        for (int ni = 0; ni < 4; ni++){
            int colL = wn*64 + ni*16 + lm;
#pragma unroll
            for (int rr = 0; rr < 4; rr++){
                int rowL = wm*64 + mi*16 + lq*4 + rr;
                smem[rowL*264 + colL] = (f16)(acc[mi][ni][rr] + dv4[ni]);
            }
        }
    }
    // drain LDS writes before the barrier so other waves' reads see them (race fix, round 4)
    asm volatile("s_waitcnt lgkmcnt(0)" ::: "memory");
    __builtin_amdgcn_s_barrier();
#pragma unroll
    for (int it = 0; it < 8; it++){
        int ch = tid + it*512;            // 4096 chunks: 128 rows x 32 col-chunks
        int rowL = ch >> 5, cc = (ch & 31)*8;
        int grow = m0 + rowL;
        if (grow < M && cc < ncols){
            if (cc + 8 <= ncols){
                f16x8 v = *(f16x8*)&smem[rowL*264 + cc];
                *(f16x8*)(C + (size_t)grow*SN + n0 + cc) = v;
            } else {
                for (int jj = cc; jj < ncols; jj++)
                    C[(size_t)grow*SN + n0 + jj] = smem[rowL*264 + jj];
            }
        }
    }
}

// ====== 128x128 MFMA GEMM (L2 layer): 4 waves, ring-3, 3 blocks/CU ======
__global__ __launch_bounds__(256, 3) void k_gemmS(const f16* __restrict__ A,
                                                  const f16* __restrict__ Bt,
                                                  const float* __restrict__ dvec,
                                                  f16* __restrict__ C,
                                                  float* __restrict__ a_sd,
                                                  int M, int N, int NB, int H,
                                                  int KP, int SN, int Mtiles, int NT){
    __shared__ f16 smem[24576];        // A ring [0,12288): 3x4096; B ring [12288,24576): 3x4096
    f16* sB = smem + 12288;

    int nwg = Mtiles*NT;
    int bid = blockIdx.x;
    int q = nwg >> 3, r = nwg & 7, xcd = bid & 7, lin = bid >> 3;
    int wg = (xcd < r ? xcd*(q+1) : r*(q+1) + (xcd - r)*q) + lin;
    int mt = wg / NT, nt = wg - mt*NT;
    int m0 = mt*128, n0 = nt*128;

    int tid = threadIdx.x;
    int w = tid >> 6, lane = tid & 63;      // 4 waves
    int lm = lane & 15, lq = lane >> 4;
    int wm = w >> 1, wn = w & 1;            // wave tile 64x64

    int kqs = ((lane & 3) ^ ((lane >> 3) & 3)) * 8;
    const f16* gA0 = A  + (size_t)min(m0 + w*32 + (lane >> 2), M-1)*KP + kqs;
    const f16* gA1 = A  + (size_t)min(m0 + w*32 + 16 + (lane >> 2), M-1)*KP + kqs;
    const f16* gB0 = Bt + (size_t)min(n0 + w*32 + (lane >> 2), NB-1)*KP + kqs;
    const f16* gB1 = Bt + (size_t)min(n0 + w*32 + 16 + (lane >> 2), NB-1)*KP + kqs;
    int sa0 = w*1024, sa1 = w*1024 + 512;
    int sb0 = w*1024, sb1 = w*1024 + 512;

    int swz  = (lq ^ ((lm >> 1) & 3)) * 8;
    int aoff = (wm*64 + lm)*32 + swz;
    int boff = (wn*64 + lm)*32 + swz;

    f32x4 acc[4][4];
#pragma unroll
    for (int i = 0; i < 4; i++)
#pragma unroll
        for (int j = 0; j < 4; j++) acc[i][j] = (f32x4)0.f;

    int KT = KP >> 5;

    async_ld16(gA0,      &smem[sa0]);        async_ld16(gA1,      &smem[sa1]);
    async_ld16(gB0,      &sB[sb0]);          async_ld16(gB1,      &sB[sb1]);
    async_ld16(gA0 + 32, &smem[4096 + sa0]); async_ld16(gA1 + 32, &smem[4096 + sa1]);
    async_ld16(gB0 + 32, &sB[4096 + sb0]);   async_ld16(gB1 + 32, &sB[4096 + sb1]);
    asm volatile("s_waitcnt vmcnt(4)" ::: "memory");
    __builtin_amdgcn_s_barrier();

    int cur = 0, nx2 = 2;
    for (int t = 0; t < KT; t++){
        int ac = cur*4096, bc = cur*4096;
        f16x8 aF[4], bF[4];
#pragma unroll
        for (int i = 0; i < 4; i++) aF[i] = *(const f16x8*)&smem[ac + aoff + i*512];
#pragma unroll
        for (int i = 0; i < 4; i++) bF[i] = *(const f16x8*)&sB[bc + boff + i*512];
        bool s2 = (t+2 < KT);
        if (s2){
            int ko2 = (t+2)*32;
            int a2 = nx2*4096, b2 = nx2*4096;
            async_ld16(gA0 + ko2, &smem[a2 + sa0]); async_ld16(gA1 + ko2, &smem[a2 + sa1]);
            async_ld16(gB0 + ko2, &sB[b2 + sb0]);   async_ld16(gB1 + ko2, &sB[b2 + sb1]);
        }
        __builtin_amdgcn_s_setprio(1);
#pragma unroll
        for (int i = 0; i < 4; i++)
#pragma unroll
            for (int j = 0; j < 4; j++)
                acc[i][j] = __builtin_amdgcn_mfma_f32_16x16x32_f16(aF[i], bF[j], acc[i][j], 0, 0, 0);
        __builtin_amdgcn_s_setprio(0);
        if (s2) asm volatile("s_waitcnt vmcnt(4)" ::: "memory");
        else    asm volatile("s_waitcnt vmcnt(0)" ::: "memory");
        __builtin_amdgcn_s_barrier();
        cur = (cur == 2) ? 0 : cur + 1;
        nx2 = (nx2 == 2) ? 0 : nx2 + 1;
    }

#pragma unroll
    for (int mi = 0; mi < 4; mi++){
#pragma unroll
        for (int ni = 0; ni < 4; ni++){
            int col = n0 + wn*64 + ni*16 + lm;
            if (col >= N && col < NB){
                int jc = col - N;
                int idx = (jc < H) ? jc : (3 + jc - H);
                float dv = dvec[col];
                int rbase = m0 + wm*64 + mi*16 + lq*4;
#pragma unroll
                for (int rr = 0; rr < 4; rr++){
                    int row = rbase + rr;
                    if (row < M) a_sd[(size_t)row*6 + idx] = acc[mi][ni][rr] + dv;
                }
            }
        }
    }

    float dv4[4];
#pragma unroll
    for (int ni = 0; ni < 4; ni++){
        int gcol = n0 + wn*64 + ni*16 + lm;
        dv4[ni] = (gcol < N) ? dvec[gcol] : 0.f;
    }
    int ncols = min(128, N - n0);
#pragma unroll
    for (int mi = 0; mi < 4; mi++){
#pragma unroll
        for (int ni = 0; ni < 4; ni++){
            int colL = wn*64 + ni*16 + lm;
#pragma unroll
            for (int rr = 0; rr < 4; rr++){
                int rowL = wm*64 + mi*16 + lq*4 + rr;
                smem[rowL*136 + colL] = (f16)(acc[mi][ni][rr] + dv4[ni]);
            }
        }
    }
    asm volatile("s_waitcnt lgkmcnt(0)" ::: "memory");
    __builtin_amdgcn_s_barrier();
#pragma unroll
    for (int it = 0; it < 8; it++){
        int ch = tid + it*256;
        int rowL = ch >> 4, cc = (ch & 15)*8;
        int grow = m0 + rowL;
        if (grow < M && cc < ncols){
            if (cc + 8 <= ncols){
                f16x8 v = *(f16x8*)&smem[rowL*136 + cc];
                *(f16x8*)(C + (size_t)grow*SN + n0 + cc) = v;
            } else {
                for (int jj = cc; jj < ncols; jj++)
                    C[(size_t)grow*SN + n0 + jj] = smem[rowL*136 + jj];
            }
        }
    }
}

// ====== L0 head-GEMM: y[:, hd*780+c] = tanh(agg_hd @ Wt_hd + bias), 128x128, ring-3 ======
// Same verified ring/hazard structure as k_gemmS. A stride KPA=800 (agg), B stride 832 (Wt).
// K range 800 (A cols 780..799 are zeros -> B pad rows irrelevant). No attention cols/dvec.
__global__ __launch_bounds__(256, 3) void k_gemmH(const f16* __restrict__ A,
                                                  const f16* __restrict__ Bt,
                                                  const float* __restrict__ bias,
                                                  f16* __restrict__ Y,
                                                  int Mtiles, int NT){
    const int KPB = 832, Mh = NN, Nh = 780, KT = KPA >> 5;   // KT = 25
    __shared__ f16 smem[24576];
    f16* sB = smem + 12288;

    int nwg = 3*Mtiles*NT;
    int bid = blockIdx.x;
    int q = nwg >> 3, r = nwg & 7, xcd = bid & 7, lin = bid >> 3;
    int wg = (xcd < r ? xcd*(q+1) : r*(q+1) + (xcd - r)*q) + lin;
    int hd = wg / (Mtiles*NT);
    int rem = wg - hd*(Mtiles*NT);
    int mt = rem / NT, nt = rem - mt*NT;
    int m0 = mt*128, n0 = nt*128;
    const f16* Ah = A  + (size_t)hd*NN*KPA;
    const f16* Bh = Bt + (size_t)hd*Nh*KPB;

    int tid = threadIdx.x;
    int w = tid >> 6, lane = tid & 63;
    int lm = lane & 15, lq = lane >> 4;
    int wm = w >> 1, wn = w & 1;

    int kqs = ((lane & 3) ^ ((lane >> 3) & 3)) * 8;
    const f16* gA0 = Ah + (size_t)min(m0 + w*32 + (lane >> 2), Mh-1)*KPA + kqs;
    const f16* gA1 = Ah + (size_t)min(m0 + w*32 + 16 + (lane >> 2), Mh-1)*KPA + kqs;
    const f16* gB0 = Bh + (size_t)min(n0 + w*32 + (lane >> 2), Nh-1)*KPB + kqs;
    const f16* gB1 = Bh + (size_t)min(n0 + w*32 + 16 + (lane >> 2), Nh-1)*KPB + kqs;
    int sa0 = w*1024, sa1 = w*1024 + 512;

    int swz  = (lq ^ ((lm >> 1) & 3)) * 8;
    int aoff = (wm*64 + lm)*32 + swz;
    int boff = (wn*64 + lm)*32 + swz;

    f32x4 acc[4][4];
#pragma unroll
    for (int i = 0; i < 4; i++)
#pragma unroll
        for (int j = 0; j < 4; j++) acc[i][j] = (f32x4)0.f;

    async_ld16(gA0,      &smem[sa0]);        async_ld16(gA1,      &smem[sa1]);
    async_ld16(gB0,      &sB[sa0]);          async_ld16(gB1,      &sB[sa1]);
    async_ld16(gA0 + 32, &smem[4096 + sa0]); async_ld16(gA1 + 32, &smem[4096 + sa1]);
    async_ld16(gB0 + 32, &sB[4096 + sa0]);   async_ld16(gB1 + 32, &sB[4096 + sa1]);
    asm volatile("s_waitcnt vmcnt(4)" ::: "memory");
    __builtin_amdgcn_s_barrier();

    int cur = 0, nx2 = 2;
    for (int t = 0; t < KT; t++){
        int ac = cur*4096;
        f16x8 aF[4], bF[4];
#pragma unroll
        for (int i = 0; i < 4; i++) aF[i] = *(const f16x8*)&smem[ac + aoff + i*512];
#pragma unroll
        for (int i = 0; i < 4; i++) bF[i] = *(const f16x8*)&sB[ac + boff + i*512];
        bool s2 = (t+2 < KT);
        if (s2){
            int ko2 = (t+2)*32;
            int a2 = nx2*4096;
            async_ld16(gA0 + ko2, &smem[a2 + sa0]); async_ld16(gA1 + ko2, &smem[a2 + sa1]);
            async_ld16(gB0 + ko2, &sB[a2 + sa0]);   async_ld16(gB1 + ko2, &sB[a2 + sa1]);
        }
        __builtin_amdgcn_s_setprio(1);
#pragma unroll
        for (int i = 0; i < 4; i++)
#pragma unroll
            for (int j = 0; j < 4; j++)
                acc[i][j] = __builtin_amdgcn_mfma_f32_16x16x32_f16(aF[i], bF[j], acc[i][j], 0, 0, 0);
        __builtin_amdgcn_s_setprio(0);
        if (s2) asm volatile("s_waitcnt vmcnt(4)" ::: "memory");
        else    asm volatile("s_waitcnt vmcnt(0)" ::: "memory");
        __builtin_amdgcn_s_barrier();
        cur = (cur == 2) ? 0 : cur + 1;
        nx2 = (nx2 == 2) ? 0 : nx2 + 1;
    }

    // epilogue: tanh(acc + bias), staged via LDS, coalesced f16x4-pair stores
    float bv[4];
#pragma unroll
    for (int ni = 0; ni < 4; ni++){
        int col = n0 + wn*64 + ni*16 + lm;
        bv[ni] = (col < Nh) ? bias[hd*Nh + col] : 0.f;
    }
    int ncols = min(128, Nh - n0);
#pragma unroll
    for (int mi = 0; mi < 4; mi++){
#pragma unroll
        for (int ni = 0; ni < 4; ni++){
            int colL = wn*64 + ni*16 + lm;
#pragma unroll
            for (int rr = 0; rr < 4; rr++){
                int rowL = wm*64 + mi*16 + lq*4 + rr;
                smem[rowL*136 + colL] = (f16)tanhf(acc[mi][ni][rr] + bv[ni]);
            }
        }
    }
    asm volatile("s_waitcnt lgkmcnt(0)" ::: "memory");
    __builtin_amdgcn_s_barrier();
#pragma unroll
    for (int it = 0; it < 8; it++){
        int ch = tid + it*256;
        int rowL = ch >> 4, cc = (ch & 15)*8;
        int grow = m0 + rowL;
        if (grow < Mh && cc < ncols){
            size_t gb = (size_t)grow*W3P + hd*Nh + n0 + cc;   // 8B-aligned (hd*1560B)
            if (cc + 8 <= ncols){
                *(f16x4*)(Y + gb)     = *(f16x4*)&smem[rowL*136 + cc];
                *(f16x4*)(Y + gb + 4) = *(f16x4*)&smem[rowL*136 + cc + 4];
            } else {
                for (int jj = cc; jj < ncols; jj++)
                    Y[(size_t)grow*W3P + hd*Nh + n0 + jj] = smem[rowL*136 + jj];
            }
        }
    }
}

// ---- L0: a_sd = h @ w_att (skinny), wave-per-node ----
template<int H>
__global__ __launch_bounds__(256) void k_asd(const f16* __restrict__ h, const f16* __restrict__ watt,
                                             const float* __restrict__ dvN, float* __restrict__ a_sd,
                                             int KP){
    int n = blockIdx.x*4 + (threadIdx.x >> 6);
    if (n >= NN) return;
    int lane = threadIdx.x & 63;
    const f16* hr = h + (size_t)n*KP;
    float acc[2*H];
#pragma unroll
    for (int i = 0; i < 2*H; i++) acc[i] = 0.f;
    for (int k0 = 0; k0 < KP; k0 += 64){
        float hv = (float)hr[k0 + lane];
#pragma unroll
        for (int i = 0; i < 2*H; i++)
            acc[i] += hv * (float)watt[(size_t)i*KP + k0 + lane];
    }
#pragma unroll
    for (int off = 32; off; off >>= 1)
#pragma unroll
        for (int i = 0; i < 2*H; i++) acc[i] += __shfl_xor(acc[i], off);
    if (lane == 0){
#pragma unroll
        for (int i = 0; i < 2*H; i++){
            int idx = (i < H) ? i : (3 + i - H);
            a_sd[(size_t)n*6 + idx] = acc[i] + dvN[i];
        }
    }
}

// ---- L0: gather-first. agg[hd][n][k] = sum_e alpha_e^hd * h[src_e][k] ----
// One 1.66KB row read feeds ALL 3 head accumulators (the traffic win: 474->166 MB).
// h cols [780,832) are zero -> agg pads [780,800) are zero automatically.
__global__ __launch_bounds__(256) void k_gagg(const f16* __restrict__ h, const int* __restrict__ rp,
                                              const int* __restrict__ csrc, const float* __restrict__ alpha,
                                              f16* __restrict__ agg){
    int w = threadIdx.x >> 6, lane = threadIdx.x & 63;
    int n = blockIdx.x*4 + w;
    if (n >= NN) return;
    int beg = rp[n], deg = rp[n+1] - beg;
    int c0 = lane*8, c1 = 512 + lane*8;
    bool ok1 = c1 < KPA;   // lanes 0..35 cover cols 512..799

    float acc[3][2][8];
#pragma unroll
    for (int hd = 0; hd < 3; hd++)
#pragma unroll
        for (int g = 0; g < 2; g++)
#pragma unroll
            for (int j = 0; j < 8; j++) acc[hd][g][j] = 0.f;

    for (int base = 0; base < deg; base += 64){
        int cnt = min(64, deg - base);
        int e0 = base + lane;
        int sl = 0; float a0v = 0.f, a1v = 0.f, a2v = 0.f;
        if (e0 < deg){
            sl = csrc[beg + e0];
            float4 q4 = *(const float4*)(alpha + (size_t)(beg+e0)*4);
            a0v = q4.x; a1v = q4.y; a2v = q4.z;
        }
#pragma unroll 4
        for (int e = 0; e < cnt; e++){
            int s = __shfl(sl, e);
            float b0 = __shfl(a0v, e);
            float b1 = __shfl(a1v, e);
            float b2 = __shfl(a2v, e);
            const f16* row = h + (size_t)s*EMBP;
            f16x8 v0 = *(const f16x8*)(row + c0);
#pragma unroll
            for (int j = 0; j < 8; j++){
                float vv = (float)v0[j];
                acc[0][0][j] += b0*vv; acc[1][0][j] += b1*vv; acc[2][0][j] += b2*vv;
            }
            if (ok1){
                f16x8 v1 = *(const f16x8*)(row + c1);
#pragma unroll
                for (int j = 0; j < 8; j++){
                    float vv = (float)v1[j];
                    acc[0][1][j] += b0*vv; acc[1][1][j] += b1*vv; acc[2][1][j] += b2*vv;
                }
            }
        }
    }

#pragma unroll
    for (int hd = 0; hd < 3; hd++){
        f16x8 o;
#pragma unroll
        for (int j = 0; j < 8; j++) o[j] = (f16)acc[hd][0][j];
        *(f16x8*)(agg + ((size_t)hd*NN + n)*KPA + c0) = o;
        if (ok1){
            f16x8 o1;
#pragma unroll
            for (int j = 0; j < 8; j++) o1[j] = (f16)acc[hd][1][j];
            *(f16x8*)(agg + ((size_t)hd*NN + n)*KPA + c1) = o1;
        }
    }
}

// ---- phase 1: per-node softmax -> per-edge alpha (f32) ----
template<int H>
__global__ __launch_bounds__(256) void k_alpha(const int* __restrict__ rp, const int* __restrict__ csrc,
                                               const float* __restrict__ a_sd, float* __restrict__ alpha){
    int n = blockIdx.x*4 + (threadIdx.x >> 6);
    if (n >= NN) return;
    int lane = threadIdx.x & 63;
    int beg = rp[n], deg = rp[n+1] - beg;

    float adv[H];
#pragma unroll
    for (int h = 0; h < H; h++) adv[h] = a_sd[(size_t)n*6 + 3 + h];

    bool act0 = lane < deg;
    int sl0 = 0; float t0[H];
    if (act0){
        sl0 = csrc[beg + lane];
#pragma unroll
        for (int h = 0; h < H; h++){
            float t = a_sd[(size_t)sl0*6 + h] + adv[h];
            t0[h] = t > 0.f ? t : 0.2f*t;
        }
    } else {
#pragma unroll
        for (int h = 0; h < H; h++) t0[h] = -1e30f;
    }

    float mx[H];
#pragma unroll
    for (int h = 0; h < H; h++) mx[h] = t0[h];
    for (int base = 64; base < deg; base += 64){
        int e = base + lane;
        if (e < deg){
            int s = csrc[beg + e];
#pragma unroll
            for (int h = 0; h < H; h++){
                float t = a_sd[(size_t)s*6 + h] + adv[h];
                t = t > 0.f ? t : 0.2f*t;
                mx[h] = fmaxf(mx[h], t);
            }
        }
    }
#pragma unroll
    for (int off = 32; off; off >>= 1)
#pragma unroll
        for (int h = 0; h < H; h++) mx[h] = fmaxf(mx[h], __shfl_xor(mx[h], off));

    float dn[H];
#pragma unroll
    for (int h = 0; h < H; h++) dn[h] = act0 ? expf(t0[h] - mx[h]) : 0.f;
    for (int base = 64; base < deg; base += 64){
        int e = base + lane;
        if (e < deg){
            int s = csrc[beg + e];
#pragma unroll
            for (int h = 0; h < H; h++){
                float t = a_sd[(size_t)s*6 + h] + adv[h];
                t = t > 0.f ? t : 0.2f*t;
                dn[h] += expf(t - mx[h]);
            }
        }
    }
#pragma unroll
    for (int off = 32; off; off >>= 1)
#pragma unroll
        for (int h = 0; h < H; h++) dn[h] += __shfl_xor(dn[h], off);
    float inv[H];
#pragma unroll
    for (int h = 0; h < H; h++) inv[h] = 1.f / (dn[h] + 1e-16f);

    if (act0){
        if (H == 3){
            float4 o;
            o.x = expf(t0[0]-mx[0])*inv[0];
            o.y = expf(t0[1]-mx[1])*inv[1];
            o.z = expf(t0[2]-mx[2])*inv[2];
            o.w = 0.f;
            *(float4*)(alpha + (size_t)(beg+lane)*4) = o;
        } else {
            alpha[beg+lane] = expf(t0[0]-mx[0])*inv[0];
        }
    }
    for (int base = 64; base < deg; base += 64){
        int e = base + lane;
        if (e < deg){
            int s = csrc[beg + e];
            float av[H];
#pragma unroll
            for (int h = 0; h < H; h++){
                float t = a_sd[(size_t)s*6 + h] + adv[h];
                t = t > 0.f ? t : 0.2f*t;
                av[h] = expf(t - mx[h]) * inv[h];
            }
            if (H == 3){
                float4 o; o.x = av[0]; o.y = av[1]; o.z = av[2]; o.w = 0.f;
                *(float4*)(alpha + (size_t)(beg+e)*4) = o;
            } else {
                alpha[beg+e] = av[0];
            }
        }
    }
}

// ---- phase 2 (L1/L2): gather. Wave-per-(node, 512-col group) ----
template<int H>
__global__ __launch_bounds__(256) void k_gather(const f16* __restrict__ hp, const int* __restrict__ rp,
                                                const int* __restrict__ csrc, const float* __restrict__ alpha,
                                                const float* __restrict__ bias, f16* __restrict__ y,
                                                int SP, int W){
    int w = threadIdx.x >> 6, lane = threadIdx.x & 63;
    int n = blockIdx.x*4 + w;
    if (n >= NN) return;
    int c = blockIdx.y*512 + lane*8;
    bool cok = c < SP;
    int beg = rp[n], deg = rp[n+1] - beg;

    int hl = 0, hh = 0, nsp = 8;
    if (H == 3){
        hl = min(c/EMB, 2); hh = min((c+7)/EMB, 2);
        nsp = (hh > hl) ? (EMB*(hl+1) - c) : 8;
    }
    float acc[8];
#pragma unroll
    for (int j = 0; j < 8; j++) acc[j] = 0.f;

    for (int base = 0; base < deg; base += 64){
        int cnt = min(64, deg - base);
        int e0 = base + lane;
        int sl = 0; float a0v = 0.f, a1v = 0.f, a2v = 0.f;
        if (e0 < deg){
            sl = csrc[beg + e0];
            if (H == 3){
                float4 al4 = *(const float4*)(alpha + (size_t)(beg+e0)*4);
                a0v = al4.x; a1v = al4.y; a2v = al4.z;
            } else {
                a0v = alpha[beg + e0];
            }
        }
#pragma unroll 4
        for (int e = 0; e < cnt; e++){
            int s = __shfl(sl, e);
            float b0 = __shfl(a0v, e);
            float b1 = (H==3) ? __shfl(a1v, e) : b0;
            float b2 = (H==3) ? __shfl(a2v, e) : b0;
            if (cok){
                f16x8 v = *(const f16x8*)(hp + (size_t)s*SP + c);
                float lo = (H==3) ? ((hl==0)?b0:((hl==1)?b1:b2)) : b0;
                float hi = (H==3) ? ((hh==0)?b0:((hh==1)?b1:b2)) : b0;
#pragma unroll
                for (int j = 0; j < 8; j++)
                    acc[j] += ((j < nsp) ? lo : hi) * (float)v[j];
            }
        }
    }

    if (cok){
        f16x8 o;
#pragma unroll
        for (int j = 0; j < 8; j++){
            float vv = (c + j < W) ? tanhf(acc[j] + bias[c+j]) : 0.f;
            o[j] = (f16)vv;
        }
        *(f16x8*)(y + (size_t)n*SP + c) = o;
    }
}

// ---------------- BatchNorm stats: contiguous-row-range partials (no atomics) ----------------
__global__ void k_bnstat(const f16* __restrict__ y, float* __restrict__ ps,
                         float* __restrict__ pq, int W, int SP){
    int c0 = (blockIdx.x*256 + threadIdx.x)*4;
    if (c0 >= W) return;
    int slice = blockIdx.y;   // 0..127
    int r0 = (int)(((long long)NN*slice)/128);
    int r1 = (int)(((long long)NN*(slice+1))/128);
    float s[4] = {0,0,0,0}, q[4] = {0,0,0,0};
    for (int r = r0; r < r1; r++){
        f16x4 u = *(const f16x4*)(y + (size_t)r*SP + c0);
#pragma unroll
        for (int j = 0; j < 4; j++){ float v = (float)u[j]; s[j] += v; q[j] += v*v; }
    }
#pragma unroll
    for (int j = 0; j < 4; j++){
        ps[(size_t)slice*W3 + c0+j] = s[j];
        pq[(size_t)slice*W3 + c0+j] = q[j];
    }
}

// reduce partials; sc = istd*gamma, sh = beta - mu*istd*gamma; zero dvec for next layer
__global__ void k_bnfin(const float* __restrict__ ps, const float* __restrict__ pq,
                        const float* __restrict__ gamma, const float* __restrict__ beta,
                        float* __restrict__ sc, float* __restrict__ sh,
                        float* __restrict__ dvec, int W, int zn){
    int c = blockIdx.x*256 + threadIdx.x;
    if (c < W){
        float m = 0.f, q = 0.f;
        for (int s = 0; s < 128; s++){ m += ps[(size_t)s*W3 + c]; q += pq[(size_t)s*W3 + c]; }
        m *= (1.f/NN);
        float v = q * (1.f/NN) - m*m;
        float is = 1.f / sqrtf(v + 1e-5f);
        float g = gamma[c];
        sc[c] = is * g;
        sh[c] = beta[c] - m * is * g;
    }
    if (c < zn) dvec[c] = 0.f;
}

// ---------------- segmented pooling (raw y; BN folded into MLP) ----------------
__global__ void k_pool(const f16* __restrict__ h, const int* __restrict__ grp,
                       float* __restrict__ pooled){
    int g = blockIdx.x;
    int c = threadIdx.x*4;
    if (c >= EMB) return;
    int r0 = grp[g], r1 = grp[g+1];
    float s0=0.f, s1=0.f, s2=0.f, s3=0.f;
    for (int r = r0; r < r1; r++){
        f16x4 u = *(const f16x4*)(h + (size_t)r*EMBP + c);
        s0 += (float)u[0]; s1 += (float)u[1]; s2 += (float)u[2]; s3 += (float)u[3];
    }
    pooled[g*EMB + c] = s0; pooled[g*EMB + c+1] = s1;
    pooled[g*EMB + c+2] = s2; pooled[g*EMB + c+3] = s3;
}

__global__ __launch_bounds__(256) void k_mlp(const float* __restrict__ pooled, const int* __restrict__ grp,
                                             const float* __restrict__ sc, const float* __restrict__ sh,
                                             const float* __restrict__ W1, const float* __restrict__ b1,
                                             const float* __restrict__ W2, const float* __restrict__ b2,
                                             float* __restrict__ out){
    __shared__ float p[EMB];
    __shared__ float hid[128];
    int g = blockIdx.x, tid = threadIdx.x;
    int cnt = grp[g+1] - grp[g];
    float ic = 1.f / fmaxf((float)cnt, 1.f);
    for (int c = tid; c < EMB; c += 256){
        float v = pooled[g*EMB + c] * ic * sc[c] + sh[c];   // BN(mean) — affine commutes with mean
        p[c] = v > 0.f ? v : 0.f;
    }
    __syncthreads();
    if (tid < 128){
        float s = b1[tid];
        for (int k = 0; k < EMB; k++) s += p[k] * W1[k*128 + tid];
        hid[tid] = tanhf(s);
    }
    __syncthreads();
    if (tid < 64){
        float s = b2[tid];
        for (int k = 0; k < 128; k++) s += hid[k] * W2[k*64 + tid];
        out[g*64 + tid] = s;
    }
}

// ---------------- launch ----------------
extern "C" void kernel_launch(void* const* d_in, const int* in_sizes, int n_in,
                              void* d_out, int out_size, void* d_ws, size_t ws_size,
                              hipStream_t stream) {
    (void)in_sizes; (void)n_in; (void)out_size;
    const float* x    = (const float*)d_in[0];
    const int*   ei   = (const int*)  d_in[1];
    const int*   batch= (const int*)  d_in[2];
    const float* tW   = (const float*)d_in[3];
    const float* tb   = (const float*)d_in[4];
    const float* W0   = (const float*)d_in[5];
    const float* as0  = (const float*)d_in[6];
    const float* ad0  = (const float*)d_in[7];
    const float* b0   = (const float*)d_in[8];
    const float* g0   = (const float*)d_in[9];
    const float* be0  = (const float*)d_in[10];
    const float* W1   = (const float*)d_in[11];
    const float* as1  = (const float*)d_in[12];
    const float* ad1  = (const float*)d_in[13];
    const float* b1   = (const float*)d_in[14];
    const float* g1   = (const float*)d_in[15];
    const float* be1  = (const float*)d_in[16];
    const float* W2   = (const float*)d_in[17];
    const float* as2  = (const float*)d_in[18];
    const float* ad2  = (const float*)d_in[19];
    const float* b2   = (const float*)d_in[20];
    const float* g2   = (const float*)d_in[21];
    const float* be2  = (const float*)d_in[22];
    const float* mW1  = (const float*)d_in[23];
    const float* mb1  = (const float*)d_in[24];
    const float* mW2  = (const float*)d_in[25];
    const float* mb2  = (const float*)d_in[26];
    float* outp = (float*)d_out;

    size_t off = 0;
    auto carve = [&](size_t bytes) -> void* {
        void* p = (char*)d_ws + off;
        off = (off + bytes + 255) & ~(size_t)255;
        return p;
    };
    f16* big1 = (f16*)carve((size_t)NN*W3P*2);          // h / y buffers
    f16* big2 = (f16*)carve((size_t)NN*W3P*2);          // hp buffer (L1/L2)
    float* psum  = (float*)carve((size_t)128*W3*4);     // bnstat partials (dead during L0 agg)
    float* psq   = (float*)carve((size_t)128*W3*4);
    f16* Wt   = (f16*)carve((size_t)NZ*W3P*2);          // transposed weights + attention rows
    float* a_sd  = (float*)carve((size_t)NN*6*4);       // [n][a_s(3), a_d(3)]
    float* sc    = (float*)carve((size_t)W3*4);
    float* sh    = (float*)carve((size_t)W3*4);
    float* dvec  = (float*)carve((size_t)NZ*4);
    float* alphab= (float*)carve((size_t)ELP*4*4);      // per-edge softmax weights (float4/H=3)
    float* pooled= (float*)carve((size_t)NGR*EMB*4);
    int*   grp   = (int*)carve((size_t)(NGR+1)*4);
    int*   deg   = (int*)carve((size_t)NN*4);           // reused as cursor
    int*   rp    = (int*)carve((size_t)(NN+1)*4);
    int*   csrc  = (int*)carve((size_t)ELP*4);

    if (ws_size < off) return;

    // agg [3][NN][KPA] f16 (96.0 MB) aliases big2(94.72)+psum(1.2)+psq(partial) — all
    // dead during its lifetime (gagg write -> gemmH read; bnstat runs after).
    f16* agg = big2;

    // CSR build
    k_zero_i32<<<cdiv_i(NN,256),256,0,stream>>>(deg, NN);
    k_deg<<<cdiv_i(ELP,256),256,0,stream>>>(ei, deg);
    k_scan<<<1,1024,0,stream>>>(deg, rp);
    k_fill<<<cdiv_i(ELP,256),256,0,stream>>>(ei, deg, csrc);
    k_grp<<<1,256,0,stream>>>(batch, grp);

    // h0 + initial dvec zero (layer 0 has no BN fold)
    k_build_h<<<cdiv_i((long long)NN*(EMBP/4),256),256,0,stream>>>(x, tW, tb, big1);
    k_zero_f32<<<cdiv_i(NZ,256),256,0,stream>>>(dvec, NZ);

    struct Layer { const float* W; const float* as; const float* ad; const float* b;
                   const float* g; const float* be; int H; int K; int KP; };
    Layer layers[3] = {
        {W0, as0, ad0, b0, g0, be0, 3, EMB, EMBP},
        {W1, as1, ad1, b1, g1, be1, 3, W3,  W3P },
        {W2, as2, ad2, b2, g2, be2, 1, W3,  W3P },
    };

    for (int L = 0; L < 3; L++){
        Layer& ly = layers[L];
        int Wout  = ly.H * EMB;                 // 2340 / 2340 / 780
        int NB    = Wout + 2*ly.H;              // + attention columns
        int SPout = (Wout == W3) ? W3P : EMBP;  // 2368 / 2368 / 832
        const float* scale = (L == 0) ? nullptr : sc;
        const float* shift = (L == 0) ? nullptr : sh;

        // Wt rows [0,Wout): scaled W^T (+ fused dvec accumulation); rows [Wout,NB): att fold
        dim3 tg(cdiv_i(Wout,32), cdiv_i(ly.KP,32));
        k_transpose<<<tg, dim3(32,8), 0, stream>>>(ly.W, Wt, scale, shift, dvec, ly.K, Wout, ly.KP);
        k_wvec<<<cdiv_i(ly.K,4),256,0,stream>>>(ly.W, ly.as, ly.ad, scale, Wt, dvec, ly.K, Wout, ly.KP, ly.H);

        if (L == 0){
            // L0: aggregate-first commutation (sum alpha = 1 -> BN/bias fold passes through).
            // a_sd via skinny product, alpha, 3-head gather on the NARROW input (166 vs 474 MB),
            // then per-head GEMM with fused tanh+bias epilogue.
            k_asd<3><<<cdiv_i(NN,4),256,0,stream>>>(big1, Wt + (size_t)Wout*ly.KP, dvec + Wout, a_sd, ly.KP);
            k_alpha<3><<<cdiv_i(NN,4),256,0,stream>>>(rp, csrc, a_sd, alphab);
            k_gagg<<<cdiv_i(NN,4),256,0,stream>>>(big1, rp, csrc, alphab, agg);
            int Mtiles = cdiv_i(NN,128), NTh = cdiv_i(780,128);   // 157 x 7 per head
            k_gemmH<<<3*Mtiles*NTh, 256, 0, stream>>>(agg, Wt, ly.b, big1, Mtiles, NTh);
            k_padzero<<<cdiv_i(NN*7,256),256,0,stream>>>(big1);
        } else {
            // hp (+ a_s/a_d) = BN(h) @ [W | w_att]
            if (L == 1){
                int Mtiles = cdiv_i(NN,128), NT = cdiv_i(NB,256);
                k_gemmT<<<Mtiles*NT, 512, 0, stream>>>(big1, Wt, dvec, big2, a_sd,
                                                       NN, Wout, NB, ly.H, ly.KP, SPout, Mtiles, NT);
            } else {
                int Mtiles = cdiv_i(NN,128), NT = cdiv_i(NB,128);
                k_gemmS<<<Mtiles*NT, 256, 0, stream>>>(big1, Wt, dvec, big2, a_sd,
                                                       NN, Wout, NB, ly.H, ly.KP, SPout, Mtiles, NT);
            }
            // softmax -> per-edge alpha, then wave-per-(node,colgroup) gather + bias + tanh
            dim3 gg(cdiv_i(NN,4), cdiv_i(SPout,512));
            if (ly.H == 3){
                k_alpha<3><<<cdiv_i(NN,4),256,0,stream>>>(rp, csrc, a_sd, alphab);
                k_gather<3><<<gg,256,0,stream>>>(big2, rp, csrc, alphab, ly.b, big1, SPout, Wout);
            } else {
                k_alpha<1><<<cdiv_i(NN,4),256,0,stream>>>(rp, csrc, a_sd, alphab);
                k_gather<1><<<gg,256,0,stream>>>(big2, rp, csrc, alphab, ly.b, big1, SPout, Wout);
            }
        }

        // BN stats + fold coefficients (+ zero dvec for next layer)
        dim3 gs(cdiv_i(Wout/4,256), 128);
        k_bnstat<<<gs,256,0,stream>>>(big1, psum, psq, Wout, SPout);
        int zn = (L < 2) ? NZ : 0;
        k_bnfin<<<cdiv_i(Wout,256),256,0,stream>>>(psum, psq, ly.g, ly.be, sc, sh, dvec, Wout, zn);
    }

    // segmented pooling (raw y) + MLP (applies final BN affine on pooled means)
    k_pool<<<NGR,256,0,stream>>>(big1, grp, pooled);
    k_mlp<<<NGR,256,0,stream>>>(pooled, grp, sc, sh, mW1, mb1, mW2, mb2, outp);
}